// Round 7
// baseline (651.562 us; speedup 1.0000x reference)
//
#include <hip/hip_runtime.h>
#include <hip/hip_fp16.h>
#include <math.h>

#define D_    256
#define NH    8
#define DHD   32
#define NLV   4
#define NPT   4
#define NVT   8
#define NSEEN 64
#define TVT   72
#define FF    1024
#define BB    2
#define LSP   21760
#define LQ    21792
#define NBQ   (BB*LQ)      // 43584
#define MT128 341          // ceil(NBQ/128)

typedef __attribute__((ext_vector_type(8))) short short8;
typedef __attribute__((ext_vector_type(4))) float f32x4;

__device__ __forceinline__ unsigned short f2bf(float f)
{
    unsigned int u = __float_as_uint(f);
    u += 0x7fffu + ((u >> 16) & 1u);
    return (unsigned short)(u >> 16);
}
__device__ __forceinline__ float bf2f(unsigned short u) { return __uint_as_float((unsigned)u << 16); }
__device__ __forceinline__ __half2 u2h(unsigned int u) { return *(__half2*)&u; }
__device__ __forceinline__ unsigned int pack2(float a, float b)
{
    __half2 h = __halves2half2(__float2half_rn(a), __float2half_rn(b));
    return *(unsigned int*)&h;
}

__device__ __forceinline__ void gll16(const unsigned short* g, short* l)
{
    __builtin_amdgcn_global_load_lds((const __attribute__((address_space(1))) unsigned int*)g,
                                     (__attribute__((address_space(3))) unsigned int*)l,
                                     16, 0, 0);
}

// ---------------- batched weight transpose+convert: Wt[z][n][k] = bf16(W[z][k][n]) ----------------
struct CvtTable {
    const float* W[10];
    unsigned short* Wt[10];
    int K[10], N[10], t0[10];
};

__global__ __launch_bounds__(256) void cvt_all_k(CvtTable tab)
{
    __shared__ float T[32][33];
    const int tid = threadIdx.x;
    const int bt = blockIdx.x;
    int e = 0;
#pragma unroll
    for (int i = 1; i < 10; i++) if (bt >= tab.t0[i]) e = i;
    const int tl = bt - tab.t0[e];
    const int K = tab.K[e], N = tab.N[e];
    const int nt = N >> 5;
    const int tpz = (K >> 5) * nt;
    const int z = tl / tpz, rem = tl - z * tpz;
    const int n0 = (rem % nt) * 32, k0 = (rem / nt) * 32;
    const float* Wz = tab.W[e] + (size_t)z * K * N;
    unsigned short* Wtz = tab.Wt[e] + (size_t)z * N * K;
    const int tx = tid & 31, ty = tid >> 5;
#pragma unroll
    for (int s = 0; s < 4; s++)
        T[ty + 8 * s][tx] = Wz[(size_t)(k0 + ty + 8 * s) * N + n0 + tx];
    __syncthreads();
#pragma unroll
    for (int s = 0; s < 4; s++)
        Wtz[(size_t)(n0 + ty + 8 * s) * K + k0 + tx] = f2bf(T[tx][ty + 8 * s]);
}

// ---------------- input concat+convert ----------------
__global__ __launch_bounds__(256) void cvt_in_k(const float* __restrict__ src, const float* __restrict__ pos,
                                                const float* __restrict__ sel, unsigned short* __restrict__ a0,
                                                unsigned short* __restrict__ a1)
{
    size_t idx = ((size_t)blockIdx.x * 256 + threadIdx.x) * 4;
    int row = (int)(idx >> 8), c = (int)(idx & 255);
    int b = row / LQ, i = row - b * LQ;
    f32x4 v0, v1;
    if (i < LSP) {
        size_t g = ((size_t)b * LSP + i) * 256 + c;
        v0 = *(const f32x4*)(src + g);
        f32x4 p = *(const f32x4*)(pos + g);
        v1 = v0 + p;
    } else {
        size_t g = ((size_t)b * 32 + (i - LSP)) * 256 + c;
        v0 = *(const f32x4*)(sel + g);
        v1 = v0;
    }
    uint2 r0, r1;
    r0.x = (unsigned)f2bf(v0.x) | ((unsigned)f2bf(v0.y) << 16);
    r0.y = (unsigned)f2bf(v0.z) | ((unsigned)f2bf(v0.w) << 16);
    r1.x = (unsigned)f2bf(v1.x) | ((unsigned)f2bf(v1.y) << 16);
    r1.y = (unsigned)f2bf(v1.z) | ((unsigned)f2bf(v1.w) << 16);
    *(uint2*)(a0 + idx) = r0;
    *(uint2*)(a1 + idx) = r1;
}

// ---------------- 128x128-tile MFMA GEMM, global_load_lds staging ----------------
// MODE 1: Cb = bf16(relu)   MODE 4: Cb = fp16   MODE 5: split col<256->Cb (bias), else Cb2 (bias2), bf16
template<int MODE>
__global__ __launch_bounds__(256) void mfma_gemm128_k(const unsigned short* __restrict__ A,
                                                      const unsigned short* __restrict__ B,
                                                      const float* __restrict__ bias,
                                                      const float* __restrict__ bias2,
                                                      unsigned short* __restrict__ Cb,
                                                      unsigned short* __restrict__ Cb2,
                                                      int M, int K, int N)
{
    __shared__ __align__(16) short As[4096];
    __shared__ __align__(16) short Bs[4096];
    const int tid = threadIdx.x;
    const int row0 = blockIdx.x * 128;
    const int n0 = blockIdx.y * 128;
    const int w = tid >> 6, lane = tid & 63;
    const int r16 = lane & 15, q = lane >> 4;
    const int wm = w >> 1, wn = w & 1;

    int ar0 = min(row0 + w * 16 + r16, M - 1);
    int ar1 = min(row0 + (w + 4) * 16 + r16, M - 1);
    const unsigned short* gA0 = A + (size_t)ar0 * K + q * 8;
    const unsigned short* gA1 = A + (size_t)ar1 * K + q * 8;
    const unsigned short* gB0 = B + (size_t)(n0 + w * 16 + r16) * K + q * 8;
    const unsigned short* gB1 = B + (size_t)(n0 + (w + 4) * 16 + r16) * K + q * 8;
    short* sA0 = As + ((w * 4 + q) * 16 + r16) * 8;
    short* sA1 = As + (((w + 4) * 4 + q) * 16 + r16) * 8;
    short* sB0 = Bs + ((w * 4 + q) * 16 + r16) * 8;
    short* sB1 = Bs + (((w + 4) * 4 + q) * 16 + r16) * 8;

    f32x4 acc[4][4] = {};
    for (int k0 = 0; k0 < K; k0 += 32) {
        gll16(gA0 + k0, sA0);
        gll16(gA1 + k0, sA1);
        gll16(gB0 + k0, sB0);
        gll16(gB1 + k0, sB1);
        __syncthreads();
        short8 af[4], bf[4];
#pragma unroll
        for (int i = 0; i < 4; i++) af[i] = *(const short8*)(As + (((wm * 4 + i) * 4 + q) * 16 + r16) * 8);
#pragma unroll
        for (int j = 0; j < 4; j++) bf[j] = *(const short8*)(Bs + (((wn * 4 + j) * 4 + q) * 16 + r16) * 8);
#pragma unroll
        for (int i = 0; i < 4; i++)
#pragma unroll
            for (int j = 0; j < 4; j++)
                acc[i][j] = __builtin_amdgcn_mfma_f32_16x16x32_bf16(af[i], bf[j], acc[i][j], 0, 0, 0);
        __syncthreads();
    }
#pragma unroll
    for (int j = 0; j < 4; j++) {
        int col = n0 + wn * 64 + j * 16 + r16;
        float bj = (MODE == 5) ? (col < 256 ? bias[col] : bias2[col - 256]) : bias[col];
#pragma unroll
        for (int i = 0; i < 4; i++) {
#pragma unroll
            for (int ii = 0; ii < 4; ii++) {
                int row = row0 + wm * 64 + i * 16 + q * 4 + ii;
                if (row >= M) continue;
                float v = acc[i][j][ii] + bj;
                if (MODE == 1)      Cb[(size_t)row * N + col] = f2bf(fmaxf(v, 0.f));
                else if (MODE == 4) { __half hv = __float2half(v); Cb[(size_t)row * N + col] = *(unsigned short*)&hv; }
                else {
                    if (col < 256) Cb[(size_t)row * 256 + col] = f2bf(v);
                    else           Cb2[(size_t)row * 384 + col - 256] = f2bf(v);
                }
            }
        }
    }
}

// ---------------- fused GEMM (N=256 full row) + bias + residual + LayerNorm ----------------
// PHASE 0: resid = rsp/rtail f32; write ONLY xbf bf16. PHASE 1: resid = residb bf16; write dsp/dtail f32.
template<int PHASE>
__global__ __launch_bounds__(256) void gemm_ln_k(const unsigned short* __restrict__ A,
                                                 const unsigned short* __restrict__ B,
                                                 const float* __restrict__ bias,
                                                 const float* __restrict__ g, const float* __restrict__ be,
                                                 const float* __restrict__ rsp, const float* __restrict__ rtail,
                                                 const unsigned short* __restrict__ residb,
                                                 float* __restrict__ dsp, float* __restrict__ dtail,
                                                 unsigned short* __restrict__ xbf, int K)
{
    __shared__ __align__(16) short As[4096];   // 128x32
    __shared__ __align__(16) short Bs[8192];   // 256x32
    const int tid = threadIdx.x;
    const int row0 = blockIdx.x * 128;
    const int w = tid >> 6, lane = tid & 63;
    const int r16 = lane & 15, q = lane >> 4;

    const unsigned short* gA[2]; short* lA[2];
    const unsigned short* gB[4]; short* lB[4];
#pragma unroll
    for (int a = 0; a < 2; a++) {
        int idx8 = a * 256 + tid;
        int fr = idx8 >> 6, qq = (idx8 >> 4) & 3, rr = idx8 & 15;
        int row = min(row0 + fr * 16 + rr, NBQ - 1);
        gA[a] = A + (size_t)row * K + qq * 8;
        lA[a] = As + idx8 * 8;
    }
#pragma unroll
    for (int bp = 0; bp < 4; bp++) {
        int idx8 = bp * 256 + tid;
        int fr = idx8 >> 6, qq = (idx8 >> 4) & 3, rr = idx8 & 15;
        gB[bp] = B + (size_t)(fr * 16 + rr) * K + qq * 8;
        lB[bp] = Bs + idx8 * 8;
    }

    f32x4 acc[2][16] = {};
    for (int k0 = 0; k0 < K; k0 += 32) {
        gll16(gA[0] + k0, lA[0]);
        gll16(gA[1] + k0, lA[1]);
        gll16(gB[0] + k0, lB[0]);
        gll16(gB[1] + k0, lB[1]);
        gll16(gB[2] + k0, lB[2]);
        gll16(gB[3] + k0, lB[3]);
        __syncthreads();
        short8 af[2];
#pragma unroll
        for (int fm = 0; fm < 2; fm++) af[fm] = *(const short8*)(As + (((w * 2 + fm) * 4 + q) * 16 + r16) * 8);
#pragma unroll
        for (int fn = 0; fn < 16; fn++) {
            short8 bfr = *(const short8*)(Bs + ((fn * 4 + q) * 16 + r16) * 8);
            acc[0][fn] = __builtin_amdgcn_mfma_f32_16x16x32_bf16(af[0], bfr, acc[0][fn], 0, 0, 0);
            acc[1][fn] = __builtin_amdgcn_mfma_f32_16x16x32_bf16(af[1], bfr, acc[1][fn], 0, 0, 0);
        }
        __syncthreads();
    }
    float* sG  = (float*)As;
    float* sBe = sG + 256;
    float* sBi = sBe + 256;
    sG[tid] = g[tid]; sBe[tid] = be[tid]; sBi[tid] = bias[tid];
    __syncthreads();

#pragma unroll
    for (int fm = 0; fm < 2; fm++) {
#pragma unroll
        for (int i = 0; i < 4; i++) {
            int row = row0 + w * 32 + fm * 16 + q * 4 + i;
            bool valid = row < NBQ;
            int bb = valid ? row / LQ : 0;
            int ir = row - bb * LQ;
            float tv[16];
            float s = 0.f, ss = 0.f;
#pragma unroll
            for (int fn = 0; fn < 16; fn++) {
                int col = fn * 16 + r16;
                float v = acc[fm][fn][i] + sBi[col];
                float rr = 0.f;
                if (valid) {
                    if (PHASE == 0) rr = (ir < LSP) ? rsp[((size_t)bb * LSP + ir) * 256 + col]
                                                    : rtail[((size_t)bb * 32 + ir - LSP) * 256 + col];
                    else            rr = bf2f(residb[(size_t)row * 256 + col]);
                }
                float t = v + rr;
                tv[fn] = t; s += t; ss += t * t;
            }
#pragma unroll
            for (int m = 1; m < 16; m <<= 1) {
                s += __shfl_xor(s, m, 64);
                ss += __shfl_xor(ss, m, 64);
            }
            float mean = s * (1.f / 256.f);
            float var = ss * (1.f / 256.f) - mean * mean;
            float rstd = rsqrtf(var + 1e-5f);
            if (valid) {
#pragma unroll
                for (int fn = 0; fn < 16; fn++) {
                    int col = fn * 16 + r16;
                    float o = (tv[fn] - mean) * rstd * sG[col] + sBe[col];
                    if (PHASE == 0) {
                        xbf[(size_t)row * 256 + col] = f2bf(o);
                    } else {
                        if (ir < LSP) dsp[((size_t)bb * LSP + ir) * 256 + col] = o;
                        else          dtail[((size_t)bb * 32 + ir - LSP) * 256 + col] = o;
                    }
                }
            }
        }
    }
}

// ---------------- deformable sampling: fused softmax + phase-split + fp16 pk-fma gather ----------------
__global__ __launch_bounds__(256) void sample_k(const unsigned short* __restrict__ value,  // fp16
                                                const unsigned short* __restrict__ offbb,  // bf16 [NBQ][256]
                                                const unsigned short* __restrict__ wallb,  // bf16 logits [NBQ][384]
                                                const float* __restrict__ refp,
                                                unsigned short* __restrict__ attn)
{
    __shared__ float SM[4][8][49];
    __shared__ float OFs[4][8][33];
    __shared__ float RPs[4][8];
    __shared__ uint2 Twt[4][4][4][8];
    __shared__ uint4 Tix[4][4][4][8];
    const int bq0 = blockIdx.x * 4;
    const int tid = threadIdx.x;
    for (int idx = tid; idx < 1536; idx += 256) {
        int qq = idx / 384, c = idx - qq * 384;
        SM[qq][c / 48][c % 48] = bf2f(wallb[(size_t)(bq0 + qq) * 384 + c]);
    }
    for (int idx = tid; idx < 1024; idx += 256) {
        int qq = idx >> 8, c = idx & 255;
        OFs[qq][c >> 5][c & 31] = bf2f(offbb[(size_t)(bq0 + qq) * 256 + c]);
    }
    if (tid < 32) RPs[tid >> 3][tid & 7] = refp[(size_t)bq0 * 8 + tid];
    __syncthreads();
    {
        int j = tid & 7, gidx = tid >> 3;
        int qq = gidx >> 3, h = gidx & 7;
        float* row = &SM[qq][h][0];
        float v[6];
#pragma unroll
        for (int k = 0; k < 6; k++) v[k] = row[j * 6 + k];
        float m = v[0];
#pragma unroll
        for (int k = 1; k < 6; k++) m = fmaxf(m, v[k]);
        m = fmaxf(m, __shfl_xor(m, 1, 64));
        m = fmaxf(m, __shfl_xor(m, 2, 64));
        m = fmaxf(m, __shfl_xor(m, 4, 64));
        float s = 0.f;
#pragma unroll
        for (int k = 0; k < 6; k++) { v[k] = __expf(v[k] - m); s += v[k]; }
        s += __shfl_xor(s, 1, 64);
        s += __shfl_xor(s, 2, 64);
        s += __shfl_xor(s, 4, 64);
        float inv = 1.f / s;
#pragma unroll
        for (int k = 0; k < 6; k++) row[j * 6 + k] = v[k] * inv;
    }
    __syncthreads();
    const int HLc[4] = {128, 64, 32, 16};
    const int S0c[4] = {0, 16384, 20480, 21504};
#pragma unroll
    for (int s = 0; s < 2; s++) {
        int tt = tid + 256 * s;
        int qq = tt >> 7, l = (tt >> 5) & 3, p = (tt >> 3) & 3, h = tt & 7;
        int Wl = HLc[l], s0 = S0c[l];
        float x = RPs[qq][l * 2 + 0] * (float)Wl - 0.5f + OFs[qq][h][l * 8 + p * 2 + 0];
        float y = RPs[qq][l * 2 + 1] * (float)Wl - 0.5f + OFs[qq][h][l * 8 + p * 2 + 1];
        float wgt = SM[qq][h][l * 12 + p];
        float x0f = floorf(x), y0f = floorf(y);
        int x0 = (int)x0f, y0 = (int)y0f;
        float fx = x - x0f, fy = y - y0f;
        float vx0 = (x0 >= 0 && x0 <= Wl - 1) ? 1.f : 0.f;
        float vx1 = (x0 >= -1 && x0 <= Wl - 2) ? 1.f : 0.f;
        float vy0 = (y0 >= 0 && y0 <= Wl - 1) ? 1.f : 0.f;
        float vy1 = (y0 >= -1 && y0 <= Wl - 2) ? 1.f : 0.f;
        float w00 = (1.f - fx) * (1.f - fy) * wgt * vx0 * vy0;
        float w01 = fx * (1.f - fy) * wgt * vx1 * vy0;
        float w10 = (1.f - fx) * fy * wgt * vx0 * vy1;
        float w11 = fx * fy * wgt * vx1 * vy1;
        int x0c = min(max(x0, 0), Wl - 1), x1c = min(max(x0 + 1, 0), Wl - 1);
        int y0c = min(max(y0, 0), Wl - 1), y1c = min(max(y0 + 1, 0), Wl - 1);
        int rb0 = (s0 + y0c * Wl) * 512, rb1 = (s0 + y1c * Wl) * 512;
        Twt[qq][l][p][h] = make_uint2(pack2(w00, w01), pack2(w10, w11));
        Tix[qq][l][p][h] = make_uint4(rb0 + x0c * 512, rb0 + x1c * 512, rb1 + x0c * 512, rb1 + x1c * 512);
    }
    __syncthreads();
    const int qs = tid >> 6, lane = tid & 63;
    const int h = lane >> 3, c4 = (lane & 7) * 4;
    const int bq = bq0 + qs, b = bq / LQ;
    const char* vbase = (const char*)value + ((size_t)b * LQ * 256 + h * 32 + c4) * 2;
    __half2 a0 = __float2half2_rn(0.f), a1 = a0;
#pragma unroll
    for (int l = 0; l < NLV; l++) {
#pragma unroll
        for (int p = 0; p < NPT; p++) {
            uint2 wp = *(const uint2*)&Twt[qs][l][p][h];
            uint4 iv = *(const uint4*)&Tix[qs][l][p][h];
            __half2 wx = u2h(wp.x), wy = u2h(wp.y);
            __half2 w00 = __low2half2(wx), w01 = __high2half2(wx);
            __half2 w10 = __low2half2(wy), w11 = __high2half2(wy);
            uint2 d;
            d = *(const uint2*)(vbase + iv.x); a0 = __hfma2(w00, u2h(d.x), a0); a1 = __hfma2(w00, u2h(d.y), a1);
            d = *(const uint2*)(vbase + iv.y); a0 = __hfma2(w01, u2h(d.x), a0); a1 = __hfma2(w01, u2h(d.y), a1);
            d = *(const uint2*)(vbase + iv.z); a0 = __hfma2(w10, u2h(d.x), a0); a1 = __hfma2(w10, u2h(d.y), a1);
            d = *(const uint2*)(vbase + iv.w); a0 = __hfma2(w11, u2h(d.x), a0); a1 = __hfma2(w11, u2h(d.y), a1);
        }
    }
#pragma unroll
    for (int j = 0; j < 32; j++) {
        int l = j >> 3, v = j & 7;
        __half2 wv = __float2half2_rn(SM[qs][h][l * 12 + 4 + v]);
        uint2 d = *(const uint2*)(vbase + (size_t)(LSP + j) * 512);
        a0 = __hfma2(wv, u2h(d.x), a0);
        a1 = __hfma2(wv, u2h(d.y), a1);
    }
    float2 f0 = __half22float2(a0), f1 = __half22float2(a1);
    ushort4 ob;
    ob.x = f2bf(f0.x); ob.y = f2bf(f0.y); ob.z = f2bf(f1.x); ob.w = f2bf(f1.y);
    *(ushort4*)(attn + (size_t)bq * 256 + h * 32 + c4) = ob;
}

// ---------------- VT: qkv GEMM with direct f32 A (xtail/seen) ----------------
__global__ __launch_bounds__(256) void vt_qkv_gemm_k(const float* __restrict__ xtail, const float* __restrict__ seen,
                                                     const unsigned short* __restrict__ B,   // wqkvT [l][768][256]
                                                     const float* __restrict__ bias,         // [l][768]
                                                     float* __restrict__ qkvf)               // [z][72][768]
{
    __shared__ __align__(16) short As[2048];
    __shared__ __align__(16) short Bs[2048];
    const int tid = threadIdx.x;
    const int z = blockIdx.z, l = z & 3, b = z >> 2;
    const int row0 = blockIdx.x * 64;
    const int n0 = blockIdx.y * 64;
    const int w = tid >> 6, lane = tid & 63;
    const int r16 = lane & 15, q = lane >> 4;

    const int t = min(row0 + w * 16 + r16, TVT - 1);
    const float* arow = (t < NVT) ? xtail + ((size_t)b * 32 + l * 8 + t) * 256
                                  : seen + (((size_t)b * 4 + l) * 64 + (t - 8)) * 256;
    const unsigned short* gbp = B + (size_t)l * 768 * 256 + (size_t)(n0 + w * 16 + r16) * 256 + q * 8;
    short* sa = As + ((w * 4 + q) * 16 + r16) * 8;
    short* sb = Bs + ((w * 4 + q) * 16 + r16) * 8;
    const int wr2 = (w >> 1) * 2, wc2 = (w & 1) * 2;

    f32x4 acc[2][2] = {};
    for (int k0 = 0; k0 < 256; k0 += 32) {
        f32x4 u0 = *(const f32x4*)(arow + k0 + q * 8);
        f32x4 u1 = *(const f32x4*)(arow + k0 + q * 8 + 4);
        short8 sv;
        sv[0] = f2bf(u0.x); sv[1] = f2bf(u0.y); sv[2] = f2bf(u0.z); sv[3] = f2bf(u0.w);
        sv[4] = f2bf(u1.x); sv[5] = f2bf(u1.y); sv[6] = f2bf(u1.z); sv[7] = f2bf(u1.w);
        *(short8*)sa = sv;
        *(short8*)sb = *(const short8*)(gbp + k0);
        __syncthreads();
        short8 af0 = *(const short8*)(As + (((wr2 + 0) * 4 + q) * 16 + r16) * 8);
        short8 af1 = *(const short8*)(As + (((wr2 + 1) * 4 + q) * 16 + r16) * 8);
        short8 bf0 = *(const short8*)(Bs + (((wc2 + 0) * 4 + q) * 16 + r16) * 8);
        short8 bf1 = *(const short8*)(Bs + (((wc2 + 1) * 4 + q) * 16 + r16) * 8);
        acc[0][0] = __builtin_amdgcn_mfma_f32_16x16x32_bf16(af0, bf0, acc[0][0], 0, 0, 0);
        acc[0][1] = __builtin_amdgcn_mfma_f32_16x16x32_bf16(af0, bf1, acc[0][1], 0, 0, 0);
        acc[1][0] = __builtin_amdgcn_mfma_f32_16x16x32_bf16(af1, bf0, acc[1][0], 0, 0, 0);
        acc[1][1] = __builtin_amdgcn_mfma_f32_16x16x32_bf16(af1, bf1, acc[1][1], 0, 0, 0);
        __syncthreads();
    }
#pragma unroll
    for (int fm = 0; fm < 2; fm++) {
#pragma unroll
        for (int fn = 0; fn < 2; fn++) {
            int col = n0 + (w & 1) * 32 + fn * 16 + r16;
            float bj = bias[l * 768 + col];
#pragma unroll
            for (int i = 0; i < 4; i++) {
                int row = row0 + (w >> 1) * 32 + fm * 16 + q * 4 + i;
                if (row >= TVT) continue;
                qkvf[((size_t)z * TVT + row) * 768 + col] = acc[fm][fn][i] + bj;
            }
        }
    }
}

// ---------------- VT attention per (b,l,h) ----------------
__global__ __launch_bounds__(128) void vt_attn_k(const float* __restrict__ qkv, unsigned short* __restrict__ o)
{
    const int z = blockIdx.x;
    const int h = z & 7, bl = z >> 3;
    __shared__ float Qs[TVT][33];
    __shared__ float Ks[TVT][DHD];
    __shared__ float Vs[TVT][DHD];
    __shared__ float Ss[TVT][73];
    const int tid = threadIdx.x;
    for (int idx = tid; idx < TVT * DHD; idx += 128) {
        int t = idx >> 5, d = idx & 31;
        const float* base = qkv + ((size_t)bl * TVT + t) * 768 + h * DHD + d;
        Qs[t][d] = base[0];
        Ks[t][d] = base[256];
        Vs[t][d] = base[512];
    }
    __syncthreads();
    if (tid < TVT) {
        const float scale = 0.17677669529663687f;
        float qr[DHD];
#pragma unroll
        for (int d = 0; d < DHD; d++) qr[d] = Qs[tid][d];
        float m = -1e30f;
        for (int k = 0; k < TVT; k++) {
            float s = 0.f;
#pragma unroll
            for (int d = 0; d < DHD; d++) s = fmaf(qr[d], Ks[k][d], s);
            s *= scale;
            Ss[tid][k] = s;
            m = fmaxf(m, s);
        }
        float sum = 0.f;
        for (int k = 0; k < TVT; k++) {
            float e = __expf(Ss[tid][k] - m);
            Ss[tid][k] = e;
            sum += e;
        }
        float inv = 1.f / sum;
        for (int d = 0; d < DHD; d++) {
            float acc = 0.f;
            for (int k = 0; k < TVT; k++) acc = fmaf(Ss[tid][k], Vs[k][d], acc);
            o[((size_t)bl * TVT + tid) * D_ + h * DHD + d] = f2bf(acc * inv);
        }
    }
}

// ---------------- VT fused GEMM(N=256) + bias + resid + LN ----------------
// MODE 0: proj+LN3 (resid = xtail/seen f32; out vts2f f32 + vts2b bf16)
// MODE 1: fc2+LN4  (resid = residf;        out routed to out_sel/out_seen f32)
template<int MODE>
__global__ __launch_bounds__(256) void vt_gemm_ln_k(const unsigned short* __restrict__ A,   // [z][72][K] bf16
                                                    const unsigned short* __restrict__ B,   // [l][256][K] bf16
                                                    const float* __restrict__ bias,         // [l][256]
                                                    const float* __restrict__ g, const float* __restrict__ be,
                                                    const float* __restrict__ xtail, const float* __restrict__ seen,
                                                    const float* __restrict__ residf,
                                                    float* __restrict__ dstf, unsigned short* __restrict__ dstb,
                                                    float* __restrict__ out_sel, float* __restrict__ out_seen,
                                                    int K)
{
    __shared__ __align__(16) short As[2048];   // 64x32
    __shared__ __align__(16) short Bs[8192];   // 256x32
    const int tid = threadIdx.x;
    const int z = blockIdx.z, l = z & 3, b = z >> 2;
    const int row0 = blockIdx.x * 64;
    const int w = tid >> 6, lane = tid & 63;
    const int r16 = lane & 15, q = lane >> 4;

    {
        int afr = tid >> 6, arr = tid & 15;
        int aq = (tid >> 4) & 3;
        int arow = min(row0 + afr * 16 + arr, TVT - 1);
        const unsigned short* gA = A + ((size_t)z * TVT + arow) * K + aq * 8;
        short* lA = As + tid * 8;
        const unsigned short* gB[4]; short* lB[4];
#pragma unroll
        for (int bp = 0; bp < 4; bp++) {
            int idx8 = bp * 256 + tid;
            int fr = idx8 >> 6, qq = (idx8 >> 4) & 3, rr = idx8 & 15;
            gB[bp] = B + (size_t)l * 256 * K + (size_t)(fr * 16 + rr) * K + qq * 8;
            lB[bp] = Bs + idx8 * 8;
        }
        f32x4 acc[16] = {};
        for (int k0 = 0; k0 < K; k0 += 32) {
            gll16(gA + k0, lA);
            gll16(gB[0] + k0, lB[0]);
            gll16(gB[1] + k0, lB[1]);
            gll16(gB[2] + k0, lB[2]);
            gll16(gB[3] + k0, lB[3]);
            __syncthreads();
            short8 af = *(const short8*)(As + ((w * 4 + q) * 16 + r16) * 8);
#pragma unroll
            for (int fn = 0; fn < 16; fn++) {
                short8 bfr = *(const short8*)(Bs + ((fn * 4 + q) * 16 + r16) * 8);
                acc[fn] = __builtin_amdgcn_mfma_f32_16x16x32_bf16(af, bfr, acc[fn], 0, 0, 0);
            }
            __syncthreads();
        }
        float* sG  = (float*)As;
        float* sBe = (float*)Bs;
        float* sBi = sBe + 256;
        sG[tid] = g[l * 256 + tid]; sBe[tid] = be[l * 256 + tid]; sBi[tid] = bias[l * 256 + tid];
        __syncthreads();
#pragma unroll
        for (int i = 0; i < 4; i++) {
            int t = row0 + w * 16 + q * 4 + i;
            bool valid = t < TVT;
            float tv[16];
            float s = 0.f, ss = 0.f;
#pragma unroll
            for (int fn = 0; fn < 16; fn++) {
                int col = fn * 16 + r16;
                float v = acc[fn][i] + sBi[col];
                float rr = 0.f;
                if (valid) {
                    if (MODE == 0) rr = (t < NVT) ? xtail[((size_t)b * 32 + l * 8 + t) * 256 + col]
                                                  : seen[(((size_t)b * 4 + l) * 64 + t - 8) * 256 + col];
                    else           rr = residf[((size_t)z * TVT + t) * 256 + col];
                }
                float u = v + rr;
                tv[fn] = u; s += u; ss += u * u;
            }
#pragma unroll
            for (int m = 1; m < 16; m <<= 1) {
                s += __shfl_xor(s, m, 64);
                ss += __shfl_xor(ss, m, 64);
            }
            float mean = s * (1.f / 256.f);
            float var = ss * (1.f / 256.f) - mean * mean;
            float rstd = rsqrtf(var + 1e-5f);
            if (valid) {
#pragma unroll
                for (int fn = 0; fn < 16; fn++) {
                    int col = fn * 16 + r16;
                    float o = (tv[fn] - mean) * rstd * sG[col] + sBe[col];
                    if (MODE == 0) {
                        dstf[((size_t)z * TVT + t) * 256 + col] = o;
                        dstb[((size_t)z * TVT + t) * 256 + col] = f2bf(o);
                    } else {
                        if (t < NVT) out_sel[((size_t)b * 32 + l * 8 + t) * 256 + col] = o;
                        else         out_seen[(((size_t)b * 4 + l) * 64 + t - 8) * 256 + col] = o;
                    }
                }
            }
        }
    }
}

// ---------------- batched MFMA GEMM (VT fc1, gelu) ----------------
template<int MODE>   // 3: Cb bf16(gelu)
__global__ __launch_bounds__(256) void mfma_bgemm_k(const unsigned short* __restrict__ A,
                                                    const unsigned short* __restrict__ B,
                                                    const float* __restrict__ bias,
                                                    float* __restrict__ Cf, unsigned short* __restrict__ Cb,
                                                    int M, int K, int N)
{
    __shared__ __align__(16) short As[2048];
    __shared__ __align__(16) short Bs[2048];
    const int tid = threadIdx.x;
    const int z = blockIdx.z, l = z & 3;
    const int row0 = blockIdx.x * 64;
    const int n0 = blockIdx.y * 64;
    const int w = tid >> 6, lane = tid & 63;
    const int r16 = lane & 15, q = lane >> 4;

    const int arow = min(row0 + w * 16 + r16, M - 1);
    const unsigned short* gap = A + (size_t)z * M * K + (size_t)arow * K + q * 8;
    const unsigned short* gbp = B + (size_t)l * N * K + (size_t)(n0 + w * 16 + r16) * K + q * 8;
    short* sa = As + ((w * 4 + q) * 16 + r16) * 8;
    short* sb = Bs + ((w * 4 + q) * 16 + r16) * 8;

    const int wr2 = (w >> 1) * 2;
    const int wc2 = (w & 1) * 2;

    f32x4 acc[2][2] = {};
    for (int k0 = 0; k0 < K; k0 += 32) {
        *(short8*)sa = *(const short8*)(gap + k0);
        *(short8*)sb = *(const short8*)(gbp + k0);
        __syncthreads();
        short8 af0 = *(const short8*)(As + (((wr2 + 0) * 4 + q) * 16 + r16) * 8);
        short8 af1 = *(const short8*)(As + (((wr2 + 1) * 4 + q) * 16 + r16) * 8);
        short8 bf0 = *(const short8*)(Bs + (((wc2 + 0) * 4 + q) * 16 + r16) * 8);
        short8 bf1 = *(const short8*)(Bs + (((wc2 + 1) * 4 + q) * 16 + r16) * 8);
        acc[0][0] = __builtin_amdgcn_mfma_f32_16x16x32_bf16(af0, bf0, acc[0][0], 0, 0, 0);
        acc[0][1] = __builtin_amdgcn_mfma_f32_16x16x32_bf16(af0, bf1, acc[0][1], 0, 0, 0);
        acc[1][0] = __builtin_amdgcn_mfma_f32_16x16x32_bf16(af1, bf0, acc[1][0], 0, 0, 0);
        acc[1][1] = __builtin_amdgcn_mfma_f32_16x16x32_bf16(af1, bf1, acc[1][1], 0, 0, 0);
        __syncthreads();
    }
#pragma unroll
    for (int fm = 0; fm < 2; fm++) {
#pragma unroll
        for (int fn = 0; fn < 2; fn++) {
            int col = n0 + (w & 1) * 32 + fn * 16 + r16;
            float bj = bias[l * N + col];
#pragma unroll
            for (int i = 0; i < 4; i++) {
                int row = row0 + (w >> 1) * 32 + fm * 16 + q * 4 + i;
                if (row >= M) continue;
                float v = acc[fm][fn][i] + bj;
                float gl = v * 0.5f * (1.f + erff(v * 0.70710678118654752f));
                Cb[(size_t)z * M * N + (size_t)row * N + col] = f2bf(gl);
            }
        }
    }
}

// ---------------- launch ----------------

extern "C" void kernel_launch(void* const* d_in, const int* in_sizes, int n_in,
                              void* d_out, int out_size, void* d_ws, size_t ws_size,
                              hipStream_t stream)
{
    const float* src      = (const float*)d_in[0];
    const float* pos      = (const float*)d_in[1];
    const float* refp     = (const float*)d_in[2];
    const float* seen     = (const float*)d_in[5];
    const float* sel      = (const float*)d_in[6];
    const float* w_off    = (const float*)d_in[7];
    const float* b_off    = (const float*)d_in[8];
    const float* w_attn   = (const float*)d_in[9];
    const float* b_attn   = (const float*)d_in[10];
    const float* w_val    = (const float*)d_in[11];
    const float* b_val    = (const float*)d_in[12];
    const float* w_out    = (const float*)d_in[13];
    const float* b_out    = (const float*)d_in[14];
    const float* g1       = (const float*)d_in[15];
    const float* be1      = (const float*)d_in[16];
    const float* w_ff1    = (const float*)d_in[17];
    const float* b_ff1    = (const float*)d_in[18];
    const float* w_ff2    = (const float*)d_in[19];
    const float* b_ff2    = (const float*)d_in[20];
    const float* g2       = (const float*)d_in[21];
    const float* be2      = (const float*)d_in[22];
    const float* vt_wqkv  = (const float*)d_in[23];
    const float* vt_bqkv  = (const float*)d_in[24];
    const float* vt_wproj = (const float*)d_in[25];
    const float* vt_bproj = (const float*)d_in[26];
    const float* vt_g3    = (const float*)d_in[27];
    const float* vt_b3    = (const float*)d_in[28];
    const float* vt_g4    = (const float*)d_in[29];
    const float* vt_b4    = (const float*)d_in[30];
    const float* vt_wfc1  = (const float*)d_in[31];
    const float* vt_bfc1  = (const float*)d_in[32];
    const float* vt_wfc2  = (const float*)d_in[33];
    const float* vt_bfc2  = (const float*)d_in[34];

    float* ws = (float*)d_ws;
    // main-phase regions (f32-word offsets)
    unsigned short* valueh = (unsigned short*)ws;              // fp16 [NBQ][256]  [0, 5578752)
    unsigned short* offbb  = (unsigned short*)(ws + 11157504); // bf16 [NBQ][256]
    unsigned short* wallb  = (unsigned short*)(ws + 22315008); // bf16 [NBQ][384]
    unsigned short* a0b  = (unsigned short*)(ws + 39051264);
    unsigned short* a1b  = (unsigned short*)(ws + 44630016);
    unsigned short* attn = (unsigned short*)(ws + 39051264);   // over a0b (dead)
    unsigned short* xb   = (unsigned short*)(ws + 44630016);   // over a1b (dead)
    unsigned short* hb   = (unsigned short*)(ws + 11157504);   // over offbb+wallb (dead)
    float* xtail = ws + 50208768;                              // [50208768, 50225152)
    unsigned short* wtb = (unsigned short*)(ws + 50225152);
    unsigned short* wvalT  = wtb;                  // 256x256
    unsigned short* wcatT  = wtb + 65536;          // 640x256 (off || attn)
    unsigned short* woutT  = wtb + 229376;         // 256x256
    unsigned short* wff1T  = wtb + 294912;         // 1024x256
    unsigned short* wff2T  = wtb + 557056;         // 256x1024
    // VT weights in always-free zone [5578752, 11157504)
    unsigned short* wqkvT  = (unsigned short*)(ws + 5578752);  // 4x768x256 -> 393216 w
    unsigned short* wprojT = (unsigned short*)(ws + 5971968);  // 4x256x256 -> 131072 w
    unsigned short* wfc1T  = (unsigned short*)(ws + 6103040);  // 4x1024x256 -> 524288 w
    unsigned short* wfc2T  = (unsigned short*)(ws + 6627328);  // 4x256x1024 -> 524288 w
    // VT temp regions over region 0 (valueh dead after sample)
    float* qkvf  = ws + 442368;                                // [442368, 884736)
    float* vts2f = ws + 147456;                                // [147456, 294912)
    unsigned short* vts2b  = (unsigned short*)(ws + 958464);
    unsigned short* obufb  = (unsigned short*)(ws + 1032192);
    unsigned short* hvtb   = (unsigned short*)(ws + 1105920);  // [1105920, 1400832)

    float* outx     = (float*)d_out;
    float* out_seen = outx + (size_t)BB * LSP * D_;
    float* out_sel  = out_seen + (size_t)BB * NLV * NSEEN * D_;

    // 1. all weight converts in one launch
    CvtTable tab;
    auto set = [&](int i, const float* W, unsigned short* Wt, int K, int N, int t0) {
        tab.W[i] = W; tab.Wt[i] = Wt; tab.K[i] = K; tab.N[i] = N; tab.t0[i] = t0;
    };
    set(0, w_val,    wvalT,          256, 256,  0);
    set(1, w_off,    wcatT,          256, 256,  64);
    set(2, w_attn,   wcatT + 65536,  256, 384,  128);
    set(3, w_out,    woutT,          256, 256,  224);
    set(4, w_ff1,    wff1T,          256, 1024, 288);
    set(5, w_ff2,    wff2T,          1024, 256, 544);
    set(6, vt_wqkv,  wqkvT,          256, 768,  800);
    set(7, vt_wproj, wprojT,         256, 256,  1568);
    set(8, vt_wfc1,  wfc1T,          256, 1024, 1824);
    set(9, vt_wfc2,  wfc2T,          1024, 256, 2848);
    cvt_all_k<<<3872, 256, 0, stream>>>(tab);
    // 2. input converts
    cvt_in_k<<<10896, 256, 0, stream>>>(src, pos, sel, a0b, a1b);
    // 3. projection GEMMs
    mfma_gemm128_k<4><<<dim3(MT128, 2), 256, 0, stream>>>(a0b, wvalT, b_val, nullptr, valueh, nullptr, NBQ, 256, 256);
    mfma_gemm128_k<5><<<dim3(MT128, 5), 256, 0, stream>>>(a1b, wcatT, b_off, b_attn, offbb, wallb, NBQ, 256, 640);
    // 4. sampling (softmax fused)
    sample_k<<<NBQ / 4, 256, 0, stream>>>(valueh, offbb, wallb, refp, attn);
    // 5. out-proj + residual + LN1 -> bf16 xb only
    gemm_ln_k<0><<<MT128, 256, 0, stream>>>(attn, woutT, b_out, g1, be1, src, sel, nullptr,
                                            nullptr, nullptr, xb, 256);
    // 6. FFN + LN2 -> f32 outx + xtail
    mfma_gemm128_k<1><<<dim3(MT128, 8), 256, 0, stream>>>(xb, wff1T, b_ff1, nullptr, hb, nullptr, NBQ, 256, 1024);
    gemm_ln_k<1><<<MT128, 256, 0, stream>>>(hb, wff2T, b_ff2, g2, be2, nullptr, nullptr, xb,
                                            outx, xtail, nullptr, 1024);
    // 7. VT chain
    vt_qkv_gemm_k<<<dim3(2, 12, 8), 256, 0, stream>>>(xtail, seen, wqkvT, vt_bqkv, qkvf);
    vt_attn_k<<<BB * NLV * NH, 128, 0, stream>>>(qkvf, obufb);
    vt_gemm_ln_k<0><<<dim3(2, 1, 8), 256, 0, stream>>>(obufb, wprojT, vt_bproj, vt_g3, vt_b3,
                                                       xtail, seen, nullptr, vts2f, vts2b,
                                                       nullptr, nullptr, 256);
    mfma_bgemm_k<3><<<dim3(2, 16, 8), 256, 0, stream>>>(vts2b, wfc1T, vt_bfc1, nullptr, hvtb, TVT, 256, 1024);
    vt_gemm_ln_k<1><<<dim3(2, 1, 8), 256, 0, stream>>>(hvtb, wfc2T, vt_bfc2, vt_g4, vt_b4,
                                                       nullptr, nullptr, vts2f, nullptr, nullptr,
                                                       out_sel, out_seen, 1024);
}

// Round 10
// 548.222 us; speedup vs baseline: 1.1885x; 1.1885x over previous
//
#include <hip/hip_runtime.h>
#include <hip/hip_fp16.h>
#include <math.h>

#define D_    256
#define NH    8
#define DHD   32
#define NLV   4
#define NPT   4
#define NVT   8
#define NSEEN 64
#define TVT   72
#define FF    1024
#define BB    2
#define LSP   21760
#define LQ    21792
#define NBQ   (BB*LQ)      // 43584
#define NVROW (8*TVT)      // 576
#define MT128 341          // ceil(NBQ/128)

typedef __attribute__((ext_vector_type(8))) short short8;
typedef __attribute__((ext_vector_type(4))) float f32x4;

__device__ __forceinline__ unsigned short f2bf(float f)
{
    unsigned int u = __float_as_uint(f);
    u += 0x7fffu + ((u >> 16) & 1u);
    return (unsigned short)(u >> 16);
}
__device__ __forceinline__ float bf2f(unsigned short u) { return __uint_as_float((unsigned)u << 16); }
__device__ __forceinline__ __half2 u2h(unsigned int u) { return *(__half2*)&u; }
__device__ __forceinline__ unsigned int pack2(float a, float b)
{
    __half2 h = __halves2half2(__float2half_rn(a), __float2half_rn(b));
    return *(unsigned int*)&h;
}

__device__ __forceinline__ void gll16(const unsigned short* g, short* l)
{
    __builtin_amdgcn_global_load_lds((const __attribute__((address_space(1))) unsigned int*)g,
                                     (__attribute__((address_space(3))) unsigned int*)l,
                                     16, 0, 0);
}

// ---------------- batched weight transpose+convert: Wt[z][n][k] = bf16(W[z][k][n]) ----------------
struct CvtTable {
    const float* W[10];
    unsigned short* Wt[10];
    int K[10], N[10], t0[10];
};

__global__ __launch_bounds__(256) void cvt_all_k(CvtTable tab)
{
    __shared__ float T[32][33];
    const int tid = threadIdx.x;
    const int bt = blockIdx.x;
    int e = 0;
#pragma unroll
    for (int i = 1; i < 10; i++) if (bt >= tab.t0[i]) e = i;
    const int tl = bt - tab.t0[e];
    const int K = tab.K[e], N = tab.N[e];
    const int nt = N >> 5;
    const int tpz = (K >> 5) * nt;
    const int z = tl / tpz, rem = tl - z * tpz;
    const int n0 = (rem % nt) * 32, k0 = (rem / nt) * 32;
    const float* Wz = tab.W[e] + (size_t)z * K * N;
    unsigned short* Wtz = tab.Wt[e] + (size_t)z * N * K;
    const int tx = tid & 31, ty = tid >> 5;
#pragma unroll
    for (int s = 0; s < 4; s++)
        T[ty + 8 * s][tx] = Wz[(size_t)(k0 + ty + 8 * s) * N + n0 + tx];
    __syncthreads();
#pragma unroll
    for (int s = 0; s < 4; s++)
        Wtz[(size_t)(n0 + ty + 8 * s) * K + k0 + tx] = f2bf(T[tx][ty + 8 * s]);
}

// ---------------- input concat+convert ----------------
__global__ __launch_bounds__(256) void cvt_in_k(const float* __restrict__ src, const float* __restrict__ pos,
                                                const float* __restrict__ sel, unsigned short* __restrict__ a0,
                                                unsigned short* __restrict__ a1)
{
    size_t idx = ((size_t)blockIdx.x * 256 + threadIdx.x) * 4;
    int row = (int)(idx >> 8), c = (int)(idx & 255);
    int b = row / LQ, i = row - b * LQ;
    f32x4 v0, v1;
    if (i < LSP) {
        size_t g = ((size_t)b * LSP + i) * 256 + c;
        v0 = *(const f32x4*)(src + g);
        f32x4 p = *(const f32x4*)(pos + g);
        v1 = v0 + p;
    } else {
        size_t g = ((size_t)b * 32 + (i - LSP)) * 256 + c;
        v0 = *(const f32x4*)(sel + g);
        v1 = v0;
    }
    uint2 r0, r1;
    r0.x = (unsigned)f2bf(v0.x) | ((unsigned)f2bf(v0.y) << 16);
    r0.y = (unsigned)f2bf(v0.z) | ((unsigned)f2bf(v0.w) << 16);
    r1.x = (unsigned)f2bf(v1.x) | ((unsigned)f2bf(v1.y) << 16);
    r1.y = (unsigned)f2bf(v1.z) | ((unsigned)f2bf(v1.w) << 16);
    *(uint2*)(a0 + idx) = r0;
    *(uint2*)(a1 + idx) = r1;
}

// ---------------- 128x128-tile MFMA GEMM, global_load_lds staging ----------------
// MODE 0: Cf f32   MODE 1: Cb bf16(relu)   MODE 4: Cb fp16   MODE 5: split col<256->Cb, else Cb2, bf16
template<int MODE>
__global__ __launch_bounds__(256) void mfma_gemm128_k(const unsigned short* __restrict__ A,
                                                      const unsigned short* __restrict__ B,
                                                      const float* __restrict__ bias,
                                                      const float* __restrict__ bias2,
                                                      float* __restrict__ Cf,
                                                      unsigned short* __restrict__ Cb,
                                                      unsigned short* __restrict__ Cb2,
                                                      int M, int K, int N)
{
    __shared__ __align__(16) short As[4096];
    __shared__ __align__(16) short Bs[4096];
    const int tid = threadIdx.x;
    const int row0 = blockIdx.x * 128;
    const int n0 = blockIdx.y * 128;
    const int w = tid >> 6, lane = tid & 63;
    const int r16 = lane & 15, q = lane >> 4;
    const int wm = w >> 1, wn = w & 1;

    int ar0 = min(row0 + w * 16 + r16, M - 1);
    int ar1 = min(row0 + (w + 4) * 16 + r16, M - 1);
    const unsigned short* gA0 = A + (size_t)ar0 * K + q * 8;
    const unsigned short* gA1 = A + (size_t)ar1 * K + q * 8;
    const unsigned short* gB0 = B + (size_t)(n0 + w * 16 + r16) * K + q * 8;
    const unsigned short* gB1 = B + (size_t)(n0 + (w + 4) * 16 + r16) * K + q * 8;
    short* sA0 = As + ((w * 4 + q) * 16 + r16) * 8;
    short* sA1 = As + (((w + 4) * 4 + q) * 16 + r16) * 8;
    short* sB0 = Bs + ((w * 4 + q) * 16 + r16) * 8;
    short* sB1 = Bs + (((w + 4) * 4 + q) * 16 + r16) * 8;

    f32x4 acc[4][4] = {};
    for (int k0 = 0; k0 < K; k0 += 32) {
        gll16(gA0 + k0, sA0);
        gll16(gA1 + k0, sA1);
        gll16(gB0 + k0, sB0);
        gll16(gB1 + k0, sB1);
        __syncthreads();
        short8 af[4], bf[4];
#pragma unroll
        for (int i = 0; i < 4; i++) af[i] = *(const short8*)(As + (((wm * 4 + i) * 4 + q) * 16 + r16) * 8);
#pragma unroll
        for (int j = 0; j < 4; j++) bf[j] = *(const short8*)(Bs + (((wn * 4 + j) * 4 + q) * 16 + r16) * 8);
#pragma unroll
        for (int i = 0; i < 4; i++)
#pragma unroll
            for (int j = 0; j < 4; j++)
                acc[i][j] = __builtin_amdgcn_mfma_f32_16x16x32_bf16(af[i], bf[j], acc[i][j], 0, 0, 0);
        __syncthreads();
    }
#pragma unroll
    for (int j = 0; j < 4; j++) {
        int col = n0 + wn * 64 + j * 16 + r16;
        float bj = (MODE == 5) ? (col < 256 ? bias[col] : bias2[col - 256]) : bias[col];
#pragma unroll
        for (int i = 0; i < 4; i++) {
#pragma unroll
            for (int ii = 0; ii < 4; ii++) {
                int row = row0 + wm * 64 + i * 16 + q * 4 + ii;
                if (row >= M) continue;
                float v = acc[i][j][ii] + bj;
                if (MODE == 0)      Cf[(size_t)row * N + col] = v;
                else if (MODE == 1) Cb[(size_t)row * N + col] = f2bf(fmaxf(v, 0.f));
                else if (MODE == 4) { __half hv = __float2half(v); Cb[(size_t)row * N + col] = *(unsigned short*)&hv; }
                else {
                    if (col < 256) Cb[(size_t)row * 256 + col] = f2bf(v);
                    else           Cb2[(size_t)row * 384 + col - 256] = f2bf(v);
                }
            }
        }
    }
}

// ---------------- residual + LayerNorm (wave per row): dst = LN(y + resid); optional bf16 copy ----------------
__global__ __launch_bounds__(256) void resid_ln_k(const float* __restrict__ y, const float* __restrict__ rsp,
                                                  const float* __restrict__ rtail, const float* __restrict__ g,
                                                  const float* __restrict__ be, float* __restrict__ dsp,
                                                  float* __restrict__ dtail, unsigned short* __restrict__ dbf)
{
    const int row = blockIdx.x * 4 + (threadIdx.x >> 6);
    const int lane = threadIdx.x & 63;
    const int b = row / LQ, i = row - b * LQ;
    f32x4 yv = *(const f32x4*)(y + (size_t)row * 256 + lane * 4);
    f32x4 rv;
    size_t didx;
    float* dbase;
    if (i < LSP) { size_t gidx = ((size_t)b * LSP + i) * 256; rv = *(const f32x4*)(rsp + gidx + lane * 4); dbase = dsp; didx = gidx; }
    else         { size_t gidx = ((size_t)b * 32 + (i - LSP)) * 256; rv = *(const f32x4*)(rtail + gidx + lane * 4); dbase = dtail; didx = gidx; }
    float t0 = yv.x + rv.x, t1 = yv.y + rv.y, t2 = yv.z + rv.z, t3 = yv.w + rv.w;
    float s = t0 + t1 + t2 + t3;
    float ss = t0 * t0 + t1 * t1 + t2 * t2 + t3 * t3;
#pragma unroll
    for (int off = 32; off; off >>= 1) {
        s += __shfl_xor(s, off, 64);
        ss += __shfl_xor(ss, off, 64);
    }
    float mean = s * (1.f / 256.f);
    float var = ss * (1.f / 256.f) - mean * mean;
    float rstd = rsqrtf(var + 1e-5f);
    int c = lane * 4;
    f32x4 gv = *(const f32x4*)(g + c);
    f32x4 bv = *(const f32x4*)(be + c);
    f32x4 o;
    o.x = (t0 - mean) * rstd * gv.x + bv.x;
    o.y = (t1 - mean) * rstd * gv.y + bv.y;
    o.z = (t2 - mean) * rstd * gv.z + bv.z;
    o.w = (t3 - mean) * rstd * gv.w + bv.w;
    *(f32x4*)(dbase + didx + c) = o;
    if (dbf) {
        ushort4 ob;
        ob.x = f2bf(o.x); ob.y = f2bf(o.y); ob.z = f2bf(o.z); ob.w = f2bf(o.w);
        *(ushort4*)(dbf + (size_t)row * 256 + c) = ob;
    }
}

// ---------------- deformable sampling: fused softmax + phase-split + fp16 pk-fma gather ----------------
__global__ __launch_bounds__(256) void sample_k(const unsigned short* __restrict__ value,  // fp16
                                                const unsigned short* __restrict__ offbb,  // bf16 [NBQ][256]
                                                const unsigned short* __restrict__ wallb,  // bf16 logits [NBQ][384]
                                                const float* __restrict__ refp,
                                                unsigned short* __restrict__ attn)
{
    __shared__ float SM[4][8][49];
    __shared__ float OFs[4][8][33];
    __shared__ float RPs[4][8];
    __shared__ uint2 Twt[4][4][4][8];
    __shared__ uint4 Tix[4][4][4][8];
    const int bq0 = blockIdx.x * 4;
    const int tid = threadIdx.x;
    for (int idx = tid; idx < 1536; idx += 256) {
        int qq = idx / 384, c = idx - qq * 384;
        SM[qq][c / 48][c % 48] = bf2f(wallb[(size_t)(bq0 + qq) * 384 + c]);
    }
    for (int idx = tid; idx < 1024; idx += 256) {
        int qq = idx >> 8, c = idx & 255;
        OFs[qq][c >> 5][c & 31] = bf2f(offbb[(size_t)(bq0 + qq) * 256 + c]);
    }
    if (tid < 32) RPs[tid >> 3][tid & 7] = refp[(size_t)bq0 * 8 + tid];
    __syncthreads();
    {
        int j = tid & 7, gidx = tid >> 3;
        int qq = gidx >> 3, h = gidx & 7;
        float* row = &SM[qq][h][0];
        float v[6];
#pragma unroll
        for (int k = 0; k < 6; k++) v[k] = row[j * 6 + k];
        float m = v[0];
#pragma unroll
        for (int k = 1; k < 6; k++) m = fmaxf(m, v[k]);
        m = fmaxf(m, __shfl_xor(m, 1, 64));
        m = fmaxf(m, __shfl_xor(m, 2, 64));
        m = fmaxf(m, __shfl_xor(m, 4, 64));
        float s = 0.f;
#pragma unroll
        for (int k = 0; k < 6; k++) { v[k] = __expf(v[k] - m); s += v[k]; }
        s += __shfl_xor(s, 1, 64);
        s += __shfl_xor(s, 2, 64);
        s += __shfl_xor(s, 4, 64);
        float inv = 1.f / s;
#pragma unroll
        for (int k = 0; k < 6; k++) row[j * 6 + k] = v[k] * inv;
    }
    __syncthreads();
    const int HLc[4] = {128, 64, 32, 16};
    const int S0c[4] = {0, 16384, 20480, 21504};
#pragma unroll
    for (int s = 0; s < 2; s++) {
        int tt = tid + 256 * s;
        int qq = tt >> 7, l = (tt >> 5) & 3, p = (tt >> 3) & 3, h = tt & 7;
        int Wl = HLc[l], s0 = S0c[l];
        float x = RPs[qq][l * 2 + 0] * (float)Wl - 0.5f + OFs[qq][h][l * 8 + p * 2 + 0];
        float y = RPs[qq][l * 2 + 1] * (float)Wl - 0.5f + OFs[qq][h][l * 8 + p * 2 + 1];
        float wgt = SM[qq][h][l * 12 + p];
        float x0f = floorf(x), y0f = floorf(y);
        int x0 = (int)x0f, y0 = (int)y0f;
        float fx = x - x0f, fy = y - y0f;
        float vx0 = (x0 >= 0 && x0 <= Wl - 1) ? 1.f : 0.f;
        float vx1 = (x0 >= -1 && x0 <= Wl - 2) ? 1.f : 0.f;
        float vy0 = (y0 >= 0 && y0 <= Wl - 1) ? 1.f : 0.f;
        float vy1 = (y0 >= -1 && y0 <= Wl - 2) ? 1.f : 0.f;
        float w00 = (1.f - fx) * (1.f - fy) * wgt * vx0 * vy0;
        float w01 = fx * (1.f - fy) * wgt * vx1 * vy0;
        float w10 = (1.f - fx) * fy * wgt * vx0 * vy1;
        float w11 = fx * fy * wgt * vx1 * vy1;
        int x0c = min(max(x0, 0), Wl - 1), x1c = min(max(x0 + 1, 0), Wl - 1);
        int y0c = min(max(y0, 0), Wl - 1), y1c = min(max(y0 + 1, 0), Wl - 1);
        int rb0 = (s0 + y0c * Wl) * 512, rb1 = (s0 + y1c * Wl) * 512;
        Twt[qq][l][p][h] = make_uint2(pack2(w00, w01), pack2(w10, w11));
        Tix[qq][l][p][h] = make_uint4(rb0 + x0c * 512, rb0 + x1c * 512, rb1 + x0c * 512, rb1 + x1c * 512);
    }
    __syncthreads();
    const int qs = tid >> 6, lane = tid & 63;
    const int h = lane >> 3, c4 = (lane & 7) * 4;
    const int bq = bq0 + qs, b = bq / LQ;
    const char* vbase = (const char*)value + ((size_t)b * LQ * 256 + h * 32 + c4) * 2;
    __half2 a0 = __float2half2_rn(0.f), a1 = a0;
#pragma unroll
    for (int l = 0; l < NLV; l++) {
#pragma unroll
        for (int p = 0; p < NPT; p++) {
            uint2 wp = *(const uint2*)&Twt[qs][l][p][h];
            uint4 iv = *(const uint4*)&Tix[qs][l][p][h];
            __half2 wx = u2h(wp.x), wy = u2h(wp.y);
            __half2 w00 = __low2half2(wx), w01 = __high2half2(wx);
            __half2 w10 = __low2half2(wy), w11 = __high2half2(wy);
            uint2 d;
            d = *(const uint2*)(vbase + iv.x); a0 = __hfma2(w00, u2h(d.x), a0); a1 = __hfma2(w00, u2h(d.y), a1);
            d = *(const uint2*)(vbase + iv.y); a0 = __hfma2(w01, u2h(d.x), a0); a1 = __hfma2(w01, u2h(d.y), a1);
            d = *(const uint2*)(vbase + iv.z); a0 = __hfma2(w10, u2h(d.x), a0); a1 = __hfma2(w10, u2h(d.y), a1);
            d = *(const uint2*)(vbase + iv.w); a0 = __hfma2(w11, u2h(d.x), a0); a1 = __hfma2(w11, u2h(d.y), a1);
        }
    }
#pragma unroll
    for (int j = 0; j < 32; j++) {
        int l = j >> 3, v = j & 7;
        __half2 wv = __float2half2_rn(SM[qs][h][l * 12 + 4 + v]);
        uint2 d = *(const uint2*)(vbase + (size_t)(LSP + j) * 512);
        a0 = __hfma2(wv, u2h(d.x), a0);
        a1 = __hfma2(wv, u2h(d.y), a1);
    }
    float2 f0 = __half22float2(a0), f1 = __half22float2(a1);
    ushort4 ob;
    ob.x = f2bf(f0.x); ob.y = f2bf(f0.y); ob.z = f2bf(f1.x); ob.w = f2bf(f1.y);
    *(ushort4*)(attn + (size_t)bq * 256 + h * 32 + c4) = ob;
}

// ---------------- VT support kernels ----------------

__global__ __launch_bounds__(256) void vt_prep_k(const float* __restrict__ xtail, const float* __restrict__ seen,
                                                 float* __restrict__ vtsf, unsigned short* __restrict__ vtsb)
{
    const int row = blockIdx.x * 4 + (threadIdx.x >> 6);
    const int lane = threadIdx.x & 63;
    const int z = row / TVT, t = row - z * TVT;
    const int b = z >> 2, l = z & 3;
    const int c = lane * 4;
    f32x4 v;
    if (t < NVT) v = *(const f32x4*)(xtail + ((size_t)b * 32 + l * NVT + t) * 256 + c);
    else         v = *(const f32x4*)(seen + (((size_t)b * NLV + l) * NSEEN + (t - NVT)) * 256 + c);
    *(f32x4*)(vtsf + (size_t)row * 256 + c) = v;
    ushort4 ob;
    ob.x = f2bf(v.x); ob.y = f2bf(v.y); ob.z = f2bf(v.z); ob.w = f2bf(v.w);
    *(ushort4*)(vtsb + (size_t)row * 256 + c) = ob;
}

// batched MFMA GEMM over z=(b,l): per-level weights
template<int MODE>   // 0: Cf f32   3: Cb bf16(gelu)
__global__ __launch_bounds__(256) void mfma_bgemm_k(const unsigned short* __restrict__ A,
                                                    const unsigned short* __restrict__ B,
                                                    const float* __restrict__ bias,
                                                    float* __restrict__ Cf, unsigned short* __restrict__ Cb,
                                                    int M, int K, int N)
{
    __shared__ __align__(16) short As[2048];
    __shared__ __align__(16) short Bs[2048];
    const int tid = threadIdx.x;
    const int z = blockIdx.z, l = z & 3;
    const int row0 = blockIdx.x * 64;
    const int n0 = blockIdx.y * 64;
    const int w = tid >> 6, lane = tid & 63;
    const int r16 = lane & 15, q = lane >> 4;

    const int arow = min(row0 + w * 16 + r16, M - 1);
    const unsigned short* gap = A + (size_t)z * M * K + (size_t)arow * K + q * 8;
    const unsigned short* gbp = B + (size_t)l * N * K + (size_t)(n0 + w * 16 + r16) * K + q * 8;
    short* sa = As + ((w * 4 + q) * 16 + r16) * 8;
    short* sb = Bs + ((w * 4 + q) * 16 + r16) * 8;

    const int wr2 = (w >> 1) * 2;
    const int wc2 = (w & 1) * 2;

    f32x4 acc[2][2] = {};
    for (int k0 = 0; k0 < K; k0 += 32) {
        *(short8*)sa = *(const short8*)(gap + k0);
        *(short8*)sb = *(const short8*)(gbp + k0);
        __syncthreads();
        short8 af0 = *(const short8*)(As + (((wr2 + 0) * 4 + q) * 16 + r16) * 8);
        short8 af1 = *(const short8*)(As + (((wr2 + 1) * 4 + q) * 16 + r16) * 8);
        short8 bf0 = *(const short8*)(Bs + (((wc2 + 0) * 4 + q) * 16 + r16) * 8);
        short8 bf1 = *(const short8*)(Bs + (((wc2 + 1) * 4 + q) * 16 + r16) * 8);
        acc[0][0] = __builtin_amdgcn_mfma_f32_16x16x32_bf16(af0, bf0, acc[0][0], 0, 0, 0);
        acc[0][1] = __builtin_amdgcn_mfma_f32_16x16x32_bf16(af0, bf1, acc[0][1], 0, 0, 0);
        acc[1][0] = __builtin_amdgcn_mfma_f32_16x16x32_bf16(af1, bf0, acc[1][0], 0, 0, 0);
        acc[1][1] = __builtin_amdgcn_mfma_f32_16x16x32_bf16(af1, bf1, acc[1][1], 0, 0, 0);
        __syncthreads();
    }
#pragma unroll
    for (int fm = 0; fm < 2; fm++) {
#pragma unroll
        for (int fn = 0; fn < 2; fn++) {
            int col = n0 + (w & 1) * 32 + fn * 16 + r16;
            float bj = bias[l * N + col];
#pragma unroll
            for (int i = 0; i < 4; i++) {
                int row = row0 + (w >> 1) * 32 + fm * 16 + q * 4 + i;
                if (row >= M) continue;
                float v = acc[fm][fn][i] + bj;
                if (MODE == 0) Cf[(size_t)z * M * N + (size_t)row * N + col] = v;
                else {
                    float gl = v * 0.5f * (1.f + erff(v * 0.70710678118654752f));
                    Cb[(size_t)z * M * N + (size_t)row * N + col] = f2bf(gl);
                }
            }
        }
    }
}

__global__ __launch_bounds__(128) void vt_attn_k(const float* __restrict__ qkv, unsigned short* __restrict__ o)
{
    const int z = blockIdx.x;
    const int h = z & 7, bl = z >> 3;
    __shared__ float Qs[TVT][33];
    __shared__ float Ks[TVT][DHD];
    __shared__ float Vs[TVT][DHD];
    __shared__ float Ss[TVT][73];
    const int tid = threadIdx.x;
    for (int idx = tid; idx < TVT * DHD; idx += 128) {
        int t = idx >> 5, d = idx & 31;
        const float* base = qkv + ((size_t)bl * TVT + t) * 768 + h * DHD + d;
        Qs[t][d] = base[0];
        Ks[t][d] = base[256];
        Vs[t][d] = base[512];
    }
    __syncthreads();
    if (tid < TVT) {
        const float scale = 0.17677669529663687f;
        float qr[DHD];
#pragma unroll
        for (int d = 0; d < DHD; d++) qr[d] = Qs[tid][d];
        float m = -1e30f;
        for (int k = 0; k < TVT; k++) {
            float s = 0.f;
#pragma unroll
            for (int d = 0; d < DHD; d++) s = fmaf(qr[d], Ks[k][d], s);
            s *= scale;
            Ss[tid][k] = s;
            m = fmaxf(m, s);
        }
        float sum = 0.f;
        for (int k = 0; k < TVT; k++) {
            float e = __expf(Ss[tid][k] - m);
            Ss[tid][k] = e;
            sum += e;
        }
        float inv = 1.f / sum;
        for (int d = 0; d < DHD; d++) {
            float acc = 0.f;
            for (int k = 0; k < TVT; k++) acc = fmaf(Ss[tid][k], Vs[k][d], acc);
            o[((size_t)bl * TVT + tid) * D_ + h * DHD + d] = f2bf(acc * inv);
        }
    }
}

template<int ROUTE>
__global__ __launch_bounds__(256) void vt_ln_k(const float* __restrict__ y, const float* __restrict__ resid,
                                               const float* __restrict__ g, const float* __restrict__ be,
                                               float* __restrict__ dstf, unsigned short* __restrict__ dstb,
                                               float* __restrict__ out_sel, float* __restrict__ out_seen)
{
    const int row = blockIdx.x * 4 + (threadIdx.x >> 6);
    const int lane = threadIdx.x & 63;
    const int z = row / TVT, t = row - z * TVT;
    const int b = z >> 2, l = z & 3;
    const int c = lane * 4;
    f32x4 yv = *(const f32x4*)(y + (size_t)row * 256 + c);
    f32x4 rv = *(const f32x4*)(resid + (size_t)row * 256 + c);
    float t0 = yv.x + rv.x, t1 = yv.y + rv.y, t2 = yv.z + rv.z, t3 = yv.w + rv.w;
    float s = t0 + t1 + t2 + t3;
    float ss = t0 * t0 + t1 * t1 + t2 * t2 + t3 * t3;
#pragma unroll
    for (int off = 32; off; off >>= 1) {
        s += __shfl_xor(s, off, 64);
        ss += __shfl_xor(ss, off, 64);
    }
    float mean = s * (1.f / 256.f);
    float var = ss * (1.f / 256.f) - mean * mean;
    float rstd = rsqrtf(var + 1e-5f);
    f32x4 gv = *(const f32x4*)(g + l * 256 + c);
    f32x4 bv = *(const f32x4*)(be + l * 256 + c);
    f32x4 o;
    o.x = (t0 - mean) * rstd * gv.x + bv.x;
    o.y = (t1 - mean) * rstd * gv.y + bv.y;
    o.z = (t2 - mean) * rstd * gv.z + bv.z;
    o.w = (t3 - mean) * rstd * gv.w + bv.w;
    if (ROUTE == 0) {
        *(f32x4*)(dstf + (size_t)row * 256 + c) = o;
        ushort4 ob;
        ob.x = f2bf(o.x); ob.y = f2bf(o.y); ob.z = f2bf(o.z); ob.w = f2bf(o.w);
        *(ushort4*)(dstb + (size_t)row * 256 + c) = ob;
    } else {
        if (t < NVT) *(f32x4*)(out_sel + ((size_t)b * 32 + l * NVT + t) * 256 + c) = o;
        else         *(f32x4*)(out_seen + (((size_t)b * NLV + l) * NSEEN + (t - NVT)) * 256 + c) = o;
    }
}

// ---------------- launch ----------------

extern "C" void kernel_launch(void* const* d_in, const int* in_sizes, int n_in,
                              void* d_out, int out_size, void* d_ws, size_t ws_size,
                              hipStream_t stream)
{
    const float* src      = (const float*)d_in[0];
    const float* pos      = (const float*)d_in[1];
    const float* refp     = (const float*)d_in[2];
    const float* seen     = (const float*)d_in[5];
    const float* sel      = (const float*)d_in[6];
    const float* w_off    = (const float*)d_in[7];
    const float* b_off    = (const float*)d_in[8];
    const float* w_attn   = (const float*)d_in[9];
    const float* b_attn   = (const float*)d_in[10];
    const float* w_val    = (const float*)d_in[11];
    const float* b_val    = (const float*)d_in[12];
    const float* w_out    = (const float*)d_in[13];
    const float* b_out    = (const float*)d_in[14];
    const float* g1       = (const float*)d_in[15];
    const float* be1      = (const float*)d_in[16];
    const float* w_ff1    = (const float*)d_in[17];
    const float* b_ff1    = (const float*)d_in[18];
    const float* w_ff2    = (const float*)d_in[19];
    const float* b_ff2    = (const float*)d_in[20];
    const float* g2       = (const float*)d_in[21];
    const float* be2      = (const float*)d_in[22];
    const float* vt_wqkv  = (const float*)d_in[23];
    const float* vt_bqkv  = (const float*)d_in[24];
    const float* vt_wproj = (const float*)d_in[25];
    const float* vt_bproj = (const float*)d_in[26];
    const float* vt_g3    = (const float*)d_in[27];
    const float* vt_b3    = (const float*)d_in[28];
    const float* vt_g4    = (const float*)d_in[29];
    const float* vt_b4    = (const float*)d_in[30];
    const float* vt_wfc1  = (const float*)d_in[31];
    const float* vt_bfc1  = (const float*)d_in[32];
    const float* vt_wfc2  = (const float*)d_in[33];
    const float* vt_bfc2  = (const float*)d_in[34];

    float* ws = (float*)d_ws;
    // ---- workspace map (f32-word offsets), lifetimes audited ----
    unsigned short* valueh = (unsigned short*)ws;              // fp16 value, words [0, 5578752)
    // VT weights: words [5578752, 6365184) — never overlapped by any main-phase buffer
    unsigned short* wqkvT  = (unsigned short*)(ws + 5578752);
    unsigned short* wprojT = (unsigned short*)(ws + 5971968);
    unsigned short* wfc1T  = (unsigned short*)(ws + 6103040);
    unsigned short* wfc2T  = (unsigned short*)(ws + 6627328);  // ends word 6889472... (within [.., 11157504))
    unsigned short* offbb  = (unsigned short*)(ws + 11157504); // bf16 [NBQ][256], words [11157504, 16736256)
    unsigned short* wallb  = (unsigned short*)(ws + 22315008); // bf16 [NBQ][384], words [22315008, 30683136)
    unsigned short* a0b  = (unsigned short*)(ws + 39051264);   // words [39051264, 44630016)
    unsigned short* a1b  = (unsigned short*)(ws + 44630016);   // words [44630016, 50208768)
    unsigned short* attn = (unsigned short*)(ws + 39051264);   // over a0b (dead after value GEMM)
    unsigned short* xb   = (unsigned short*)(ws + 44630016);   // over a1b (dead after off/attn GEMM)
    float* y     = ws + 11157504;                              // f32 [NBQ][256], over dead offbb+gap
    unsigned short* hb = (unsigned short*)(ws + 11157504);     // bf16 [NBQ][1024], words [11157504, 33472512), after y dead
    float* y2    = ws + 33472512;                              // f32 [NBQ][256], words [33472512, 44630016), over dead attn
    float* xtail = ws + 50208768;                              // words [50208768, 50225152)
    unsigned short* wtb = (unsigned short*)(ws + 50225152);
    unsigned short* wvalT  = wtb;                  // 256x256
    unsigned short* wcatT  = wtb + 65536;          // 640x256 (off || attn)
    unsigned short* woutT  = wtb + 229376;         // 256x256
    unsigned short* wff1T  = wtb + 294912;         // 1024x256
    unsigned short* wff2T  = wtb + 557056;         // 256x1024
    // VT temps over region 0 (valueh dead after sample); all < word 1400832
    float* vtsf  = ws;
    float* vts2f = ws + 147456;
    float* yy    = ws + 294912;
    float* qkvf  = ws + 442368;
    unsigned short* vtsb   = (unsigned short*)(ws + 884736);
    unsigned short* vts2b  = (unsigned short*)(ws + 958464);
    unsigned short* obufb  = (unsigned short*)(ws + 1032192);
    unsigned short* hvtb   = (unsigned short*)(ws + 1105920);

    float* outx     = (float*)d_out;
    float* out_seen = outx + (size_t)BB * LSP * D_;
    float* out_sel  = out_seen + (size_t)BB * NLV * NSEEN * D_;

    // 1. all weight converts in one launch
    CvtTable tab;
    auto set = [&](int i, const float* W, unsigned short* Wt, int K, int N, int t0) {
        tab.W[i] = W; tab.Wt[i] = Wt; tab.K[i] = K; tab.N[i] = N; tab.t0[i] = t0;
    };
    set(0, w_val,    wvalT,          256, 256,  0);
    set(1, w_off,    wcatT,          256, 256,  64);
    set(2, w_attn,   wcatT + 65536,  256, 384,  128);
    set(3, w_out,    woutT,          256, 256,  224);
    set(4, w_ff1,    wff1T,          256, 1024, 288);
    set(5, w_ff2,    wff2T,          1024, 256, 544);
    set(6, vt_wqkv,  wqkvT,          256, 768,  800);
    set(7, vt_wproj, wprojT,         256, 256,  1568);
    set(8, vt_wfc1,  wfc1T,          256, 1024, 1824);
    set(9, vt_wfc2,  wfc2T,          1024, 256, 2848);
    cvt_all_k<<<3872, 256, 0, stream>>>(tab);
    // 2. input converts
    cvt_in_k<<<10896, 256, 0, stream>>>(src, pos, sel, a0b, a1b);
    // 3. projection GEMMs
    mfma_gemm128_k<4><<<dim3(MT128, 2), 256, 0, stream>>>(a0b, wvalT, b_val, nullptr, nullptr, valueh, nullptr, NBQ, 256, 256);
    mfma_gemm128_k<5><<<dim3(MT128, 5), 256, 0, stream>>>(a1b, wcatT, b_off, b_attn, nullptr, offbb, wallb, NBQ, 256, 640);
    // 4. sampling (softmax fused)
    sample_k<<<NBQ / 4, 256, 0, stream>>>(valueh, offbb, wallb, refp, attn);
    // 5. out-proj (f32 y) + resid_ln -> outx/xtail f32 + xb bf16   [round-5 validated structure]
    mfma_gemm128_k<0><<<dim3(MT128, 2), 256, 0, stream>>>(attn, woutT, b_out, nullptr, y, nullptr, nullptr, NBQ, 256, 256);
    resid_ln_k<<<NBQ / 4, 256, 0, stream>>>(y, src, sel, g1, be1, outx, xtail, xb);
    // 6. FFN: ff1 (relu bf16 hb) -> ff2 (f32 y2) -> resid_ln LN2
    mfma_gemm128_k<1><<<dim3(MT128, 8), 256, 0, stream>>>(xb, wff1T, b_ff1, nullptr, nullptr, hb, nullptr, NBQ, 256, 1024);
    mfma_gemm128_k<0><<<dim3(MT128, 2), 256, 0, stream>>>(hb, wff2T, b_ff2, nullptr, y2, nullptr, nullptr, NBQ, 1024, 256);
    resid_ln_k<<<NBQ / 4, 256, 0, stream>>>(y2, outx, xtail, g2, be2, outx, xtail, nullptr);
    // 7. VT chain (round-6/8 validated structure)
    vt_prep_k<<<NVROW / 4, 256, 0, stream>>>(xtail, seen, vtsf, vtsb);
    mfma_bgemm_k<0><<<dim3(2, 12, 8), 256, 0, stream>>>(vtsb, wqkvT, vt_bqkv, qkvf, nullptr, TVT, 256, 768);
    vt_attn_k<<<BB * NLV * NH, 128, 0, stream>>>(qkvf, obufb);
    mfma_bgemm_k<0><<<dim3(2, 4, 8),  256, 0, stream>>>(obufb, wprojT, vt_bproj, yy, nullptr, TVT, 256, 256);
    vt_ln_k<0><<<NVROW / 4, 256, 0, stream>>>(yy, vtsf, vt_g3, vt_b3, vts2f, vts2b, nullptr, nullptr);
    mfma_bgemm_k<3><<<dim3(2, 16, 8), 256, 0, stream>>>(vts2b, wfc1T, vt_bfc1, nullptr, hvtb, TVT, 256, 1024);
    mfma_bgemm_k<0><<<dim3(2, 4, 8),  256, 0, stream>>>(hvtb, wfc2T, vt_bfc2, yy, nullptr, TVT, 1024, 256);
    vt_ln_k<1><<<NVROW / 4, 256, 0, stream>>>(yy, vts2f, vt_g4, vt_b4, nullptr, nullptr, out_sel, out_seen);
}

// Round 11
// 498.000 us; speedup vs baseline: 1.3084x; 1.1008x over previous
//
#include <hip/hip_runtime.h>
#include <hip/hip_fp16.h>
#include <math.h>

#define D_    256
#define NH    8
#define DHD   32
#define NLV   4
#define NPT   4
#define NVT   8
#define NSEEN 64
#define TVT   72
#define FF    1024
#define BB    2
#define LSP   21760
#define LQ    21792
#define NBQ   (BB*LQ)      // 43584
#define NVROW (8*TVT)      // 576
#define MT128 341          // ceil(NBQ/128)

typedef __attribute__((ext_vector_type(8))) short short8;
typedef __attribute__((ext_vector_type(4))) float f32x4;

__device__ __forceinline__ unsigned short f2bf(float f)
{
    unsigned int u = __float_as_uint(f);
    u += 0x7fffu + ((u >> 16) & 1u);
    return (unsigned short)(u >> 16);
}
__device__ __forceinline__ float bf2f(unsigned short u) { return __uint_as_float((unsigned)u << 16); }
__device__ __forceinline__ __half2 u2h(unsigned int u) { return *(__half2*)&u; }
__device__ __forceinline__ unsigned int pack2(float a, float b)
{
    __half2 h = __halves2half2(__float2half_rn(a), __float2half_rn(b));
    return *(unsigned int*)&h;
}

__device__ __forceinline__ void gll16(const unsigned short* g, short* l)
{
    __builtin_amdgcn_global_load_lds((const __attribute__((address_space(1))) unsigned int*)g,
                                     (__attribute__((address_space(3))) unsigned int*)l,
                                     16, 0, 0);
}

// ---------------- batched weight transpose+convert: Wt[z][n][k] = bf16(W[z][k][n]) ----------------
struct CvtTable {
    const float* W[10];
    unsigned short* Wt[10];
    int K[10], N[10], t0[10];
};

__global__ __launch_bounds__(256) void cvt_all_k(CvtTable tab)
{
    __shared__ float T[32][33];
    const int tid = threadIdx.x;
    const int bt = blockIdx.x;
    int e = 0;
#pragma unroll
    for (int i = 1; i < 10; i++) if (bt >= tab.t0[i]) e = i;
    const int tl = bt - tab.t0[e];
    const int K = tab.K[e], N = tab.N[e];
    const int nt = N >> 5;
    const int tpz = (K >> 5) * nt;
    const int z = tl / tpz, rem = tl - z * tpz;
    const int n0 = (rem % nt) * 32, k0 = (rem / nt) * 32;
    const float* Wz = tab.W[e] + (size_t)z * K * N;
    unsigned short* Wtz = tab.Wt[e] + (size_t)z * N * K;
    const int tx = tid & 31, ty = tid >> 5;
#pragma unroll
    for (int s = 0; s < 4; s++)
        T[ty + 8 * s][tx] = Wz[(size_t)(k0 + ty + 8 * s) * N + n0 + tx];
    __syncthreads();
#pragma unroll
    for (int s = 0; s < 4; s++)
        Wtz[(size_t)(n0 + ty + 8 * s) * K + k0 + tx] = f2bf(T[tx][ty + 8 * s]);
}

// ---------------- input concat+convert ----------------
__global__ __launch_bounds__(256) void cvt_in_k(const float* __restrict__ src, const float* __restrict__ pos,
                                                const float* __restrict__ sel, unsigned short* __restrict__ a0,
                                                unsigned short* __restrict__ a1)
{
    size_t idx = ((size_t)blockIdx.x * 256 + threadIdx.x) * 4;
    int row = (int)(idx >> 8), c = (int)(idx & 255);
    int b = row / LQ, i = row - b * LQ;
    f32x4 v0, v1;
    if (i < LSP) {
        size_t g = ((size_t)b * LSP + i) * 256 + c;
        v0 = *(const f32x4*)(src + g);
        f32x4 p = *(const f32x4*)(pos + g);
        v1 = v0 + p;
    } else {
        size_t g = ((size_t)b * 32 + (i - LSP)) * 256 + c;
        v0 = *(const f32x4*)(sel + g);
        v1 = v0;
    }
    uint2 r0, r1;
    r0.x = (unsigned)f2bf(v0.x) | ((unsigned)f2bf(v0.y) << 16);
    r0.y = (unsigned)f2bf(v0.z) | ((unsigned)f2bf(v0.w) << 16);
    r1.x = (unsigned)f2bf(v1.x) | ((unsigned)f2bf(v1.y) << 16);
    r1.y = (unsigned)f2bf(v1.z) | ((unsigned)f2bf(v1.w) << 16);
    *(uint2*)(a0 + idx) = r0;
    *(uint2*)(a1 + idx) = r1;
}

// ---------------- 128x128-tile MFMA GEMM, global_load_lds staging ----------------
// MODE 0: Cf f32   MODE 1: Cb bf16(relu)   MODE 4: Cb fp16   MODE 5: split col<256->Cb, else Cb2, bf16
template<int MODE>
__global__ __launch_bounds__(256) void mfma_gemm128_k(const unsigned short* __restrict__ A,
                                                      const unsigned short* __restrict__ B,
                                                      const float* __restrict__ bias,
                                                      const float* __restrict__ bias2,
                                                      float* __restrict__ Cf,
                                                      unsigned short* __restrict__ Cb,
                                                      unsigned short* __restrict__ Cb2,
                                                      int M, int K, int N)
{
    __shared__ __align__(16) short As[4096];
    __shared__ __align__(16) short Bs[4096];
    const int tid = threadIdx.x;
    const int row0 = blockIdx.x * 128;
    const int n0 = blockIdx.y * 128;
    const int w = tid >> 6, lane = tid & 63;
    const int r16 = lane & 15, q = lane >> 4;
    const int wm = w >> 1, wn = w & 1;

    int ar0 = min(row0 + w * 16 + r16, M - 1);
    int ar1 = min(row0 + (w + 4) * 16 + r16, M - 1);
    const unsigned short* gA0 = A + (size_t)ar0 * K + q * 8;
    const unsigned short* gA1 = A + (size_t)ar1 * K + q * 8;
    const unsigned short* gB0 = B + (size_t)(n0 + w * 16 + r16) * K + q * 8;
    const unsigned short* gB1 = B + (size_t)(n0 + (w + 4) * 16 + r16) * K + q * 8;
    short* sA0 = As + ((w * 4 + q) * 16 + r16) * 8;
    short* sA1 = As + (((w + 4) * 4 + q) * 16 + r16) * 8;
    short* sB0 = Bs + ((w * 4 + q) * 16 + r16) * 8;
    short* sB1 = Bs + (((w + 4) * 4 + q) * 16 + r16) * 8;

    f32x4 acc[4][4] = {};
    for (int k0 = 0; k0 < K; k0 += 32) {
        gll16(gA0 + k0, sA0);
        gll16(gA1 + k0, sA1);
        gll16(gB0 + k0, sB0);
        gll16(gB1 + k0, sB1);
        __syncthreads();
        short8 af[4], bf[4];
#pragma unroll
        for (int i = 0; i < 4; i++) af[i] = *(const short8*)(As + (((wm * 4 + i) * 4 + q) * 16 + r16) * 8);
#pragma unroll
        for (int j = 0; j < 4; j++) bf[j] = *(const short8*)(Bs + (((wn * 4 + j) * 4 + q) * 16 + r16) * 8);
#pragma unroll
        for (int i = 0; i < 4; i++)
#pragma unroll
            for (int j = 0; j < 4; j++)
                acc[i][j] = __builtin_amdgcn_mfma_f32_16x16x32_bf16(af[i], bf[j], acc[i][j], 0, 0, 0);
        __syncthreads();
    }
#pragma unroll
    for (int j = 0; j < 4; j++) {
        int col = n0 + wn * 64 + j * 16 + r16;
        float bj = (MODE == 5) ? (col < 256 ? bias[col] : bias2[col - 256]) : bias[col];
#pragma unroll
        for (int i = 0; i < 4; i++) {
#pragma unroll
            for (int ii = 0; ii < 4; ii++) {
                int row = row0 + wm * 64 + i * 16 + q * 4 + ii;
                if (row >= M) continue;
                float v = acc[i][j][ii] + bj;
                if (MODE == 0)      Cf[(size_t)row * N + col] = v;
                else if (MODE == 1) Cb[(size_t)row * N + col] = f2bf(fmaxf(v, 0.f));
                else if (MODE == 4) { __half hv = __float2half(v); Cb[(size_t)row * N + col] = *(unsigned short*)&hv; }
                else {
                    if (col < 256) Cb[(size_t)row * 256 + col] = f2bf(v);
                    else           Cb2[(size_t)row * 384 + col - 256] = f2bf(v);
                }
            }
        }
    }
}

// ---------------- residual + LayerNorm (wave per row): dst = LN(y + resid); optional bf16 copy ----------------
__global__ __launch_bounds__(256) void resid_ln_k(const float* __restrict__ y, const float* __restrict__ rsp,
                                                  const float* __restrict__ rtail, const float* __restrict__ g,
                                                  const float* __restrict__ be, float* __restrict__ dsp,
                                                  float* __restrict__ dtail, unsigned short* __restrict__ dbf)
{
    const int row = blockIdx.x * 4 + (threadIdx.x >> 6);
    const int lane = threadIdx.x & 63;
    const int b = row / LQ, i = row - b * LQ;
    f32x4 yv = *(const f32x4*)(y + (size_t)row * 256 + lane * 4);
    f32x4 rv;
    size_t didx;
    float* dbase;
    if (i < LSP) { size_t gidx = ((size_t)b * LSP + i) * 256; rv = *(const f32x4*)(rsp + gidx + lane * 4); dbase = dsp; didx = gidx; }
    else         { size_t gidx = ((size_t)b * 32 + (i - LSP)) * 256; rv = *(const f32x4*)(rtail + gidx + lane * 4); dbase = dtail; didx = gidx; }
    float t0 = yv.x + rv.x, t1 = yv.y + rv.y, t2 = yv.z + rv.z, t3 = yv.w + rv.w;
    float s = t0 + t1 + t2 + t3;
    float ss = t0 * t0 + t1 * t1 + t2 * t2 + t3 * t3;
#pragma unroll
    for (int off = 32; off; off >>= 1) {
        s += __shfl_xor(s, off, 64);
        ss += __shfl_xor(ss, off, 64);
    }
    float mean = s * (1.f / 256.f);
    float var = ss * (1.f / 256.f) - mean * mean;
    float rstd = rsqrtf(var + 1e-5f);
    int c = lane * 4;
    f32x4 gv = *(const f32x4*)(g + c);
    f32x4 bv = *(const f32x4*)(be + c);
    f32x4 o;
    o.x = (t0 - mean) * rstd * gv.x + bv.x;
    o.y = (t1 - mean) * rstd * gv.y + bv.y;
    o.z = (t2 - mean) * rstd * gv.z + bv.z;
    o.w = (t3 - mean) * rstd * gv.w + bv.w;
    *(f32x4*)(dbase + didx + c) = o;
    if (dbf) {
        ushort4 ob;
        ob.x = f2bf(o.x); ob.y = f2bf(o.y); ob.z = f2bf(o.z); ob.w = f2bf(o.w);
        *(ushort4*)(dbf + (size_t)row * 256 + c) = ob;
    }
}

// ---------------- deformable sampling: fused softmax + phase-split + 16B fp16 pk-fma gather ----------------
// phase 2 wave layout: lane = p2*32 + h*4 + c4lane; each lane gathers 16B (8 fp16 cols) and half the points.
__global__ __launch_bounds__(256) void sample_k(const unsigned short* __restrict__ value,  // fp16
                                                const unsigned short* __restrict__ offbb,  // bf16 [NBQ][256]
                                                const unsigned short* __restrict__ wallb,  // bf16 logits [NBQ][384]
                                                const float* __restrict__ refp,
                                                unsigned short* __restrict__ attn)
{
    __shared__ float SM[4][8][49];
    __shared__ float OFs[4][8][33];
    __shared__ float RPs[4][8];
    __shared__ uint2 Twt[4][4][4][8];
    __shared__ uint4 Tix[4][4][4][8];
    const int bq0 = blockIdx.x * 4;
    const int tid = threadIdx.x;
    for (int idx = tid; idx < 1536; idx += 256) {
        int qq = idx / 384, c = idx - qq * 384;
        SM[qq][c / 48][c % 48] = bf2f(wallb[(size_t)(bq0 + qq) * 384 + c]);
    }
    for (int idx = tid; idx < 1024; idx += 256) {
        int qq = idx >> 8, c = idx & 255;
        OFs[qq][c >> 5][c & 31] = bf2f(offbb[(size_t)(bq0 + qq) * 256 + c]);
    }
    if (tid < 32) RPs[tid >> 3][tid & 7] = refp[(size_t)bq0 * 8 + tid];
    __syncthreads();
    {
        int j = tid & 7, gidx = tid >> 3;
        int qq = gidx >> 3, h = gidx & 7;
        float* row = &SM[qq][h][0];
        float v[6];
#pragma unroll
        for (int k = 0; k < 6; k++) v[k] = row[j * 6 + k];
        float m = v[0];
#pragma unroll
        for (int k = 1; k < 6; k++) m = fmaxf(m, v[k]);
        m = fmaxf(m, __shfl_xor(m, 1, 64));
        m = fmaxf(m, __shfl_xor(m, 2, 64));
        m = fmaxf(m, __shfl_xor(m, 4, 64));
        float s = 0.f;
#pragma unroll
        for (int k = 0; k < 6; k++) { v[k] = __expf(v[k] - m); s += v[k]; }
        s += __shfl_xor(s, 1, 64);
        s += __shfl_xor(s, 2, 64);
        s += __shfl_xor(s, 4, 64);
        float inv = 1.f / s;
#pragma unroll
        for (int k = 0; k < 6; k++) row[j * 6 + k] = v[k] * inv;
    }
    __syncthreads();
    const int HLc[4] = {128, 64, 32, 16};
    const int S0c[4] = {0, 16384, 20480, 21504};
#pragma unroll
    for (int s = 0; s < 2; s++) {
        int tt = tid + 256 * s;
        int qq = tt >> 7, l = (tt >> 5) & 3, p = (tt >> 3) & 3, h = tt & 7;
        int Wl = HLc[l], s0 = S0c[l];
        float x = RPs[qq][l * 2 + 0] * (float)Wl - 0.5f + OFs[qq][h][l * 8 + p * 2 + 0];
        float y = RPs[qq][l * 2 + 1] * (float)Wl - 0.5f + OFs[qq][h][l * 8 + p * 2 + 1];
        float wgt = SM[qq][h][l * 12 + p];
        float x0f = floorf(x), y0f = floorf(y);
        int x0 = (int)x0f, y0 = (int)y0f;
        float fx = x - x0f, fy = y - y0f;
        float vx0 = (x0 >= 0 && x0 <= Wl - 1) ? 1.f : 0.f;
        float vx1 = (x0 >= -1 && x0 <= Wl - 2) ? 1.f : 0.f;
        float vy0 = (y0 >= 0 && y0 <= Wl - 1) ? 1.f : 0.f;
        float vy1 = (y0 >= -1 && y0 <= Wl - 2) ? 1.f : 0.f;
        float w00 = (1.f - fx) * (1.f - fy) * wgt * vx0 * vy0;
        float w01 = fx * (1.f - fy) * wgt * vx1 * vy0;
        float w10 = (1.f - fx) * fy * wgt * vx0 * vy1;
        float w11 = fx * fy * wgt * vx1 * vy1;
        int x0c = min(max(x0, 0), Wl - 1), x1c = min(max(x0 + 1, 0), Wl - 1);
        int y0c = min(max(y0, 0), Wl - 1), y1c = min(max(y0 + 1, 0), Wl - 1);
        int rb0 = (s0 + y0c * Wl) * 512, rb1 = (s0 + y1c * Wl) * 512;
        Twt[qq][l][p][h] = make_uint2(pack2(w00, w01), pack2(w10, w11));
        Tix[qq][l][p][h] = make_uint4(rb0 + x0c * 512, rb0 + x1c * 512, rb1 + x0c * 512, rb1 + x1c * 512);
    }
    __syncthreads();
    // phase 2: 16B gathers; p2 = point-parity half-wave
    const int qs = tid >> 6, lane = tid & 63;
    const int p2 = lane >> 5;
    const int h = (lane >> 2) & 7;
    const int c8 = (lane & 3) * 8;
    const int bq = bq0 + qs, b = bq / LQ;
    const char* vbase = (const char*)value + ((size_t)b * LQ * 256 + h * 32 + c8) * 2;
    __half2 a0 = __float2half2_rn(0.f), a1 = a0, a2 = a0, a3 = a0;
#pragma unroll
    for (int it = 0; it < 8; it++) {
        const int l = it >> 1;
        const int p = (it & 1) * 2 + p2;
        uint2 wp = *(const uint2*)&Twt[qs][l][p][h];
        uint4 iv = *(const uint4*)&Tix[qs][l][p][h];
        __half2 wx = u2h(wp.x), wy = u2h(wp.y);
        __half2 w00 = __low2half2(wx), w01 = __high2half2(wx);
        __half2 w10 = __low2half2(wy), w11 = __high2half2(wy);
        uint4 d;
        d = *(const uint4*)(vbase + iv.x);
        a0 = __hfma2(w00, u2h(d.x), a0); a1 = __hfma2(w00, u2h(d.y), a1);
        a2 = __hfma2(w00, u2h(d.z), a2); a3 = __hfma2(w00, u2h(d.w), a3);
        d = *(const uint4*)(vbase + iv.y);
        a0 = __hfma2(w01, u2h(d.x), a0); a1 = __hfma2(w01, u2h(d.y), a1);
        a2 = __hfma2(w01, u2h(d.z), a2); a3 = __hfma2(w01, u2h(d.w), a3);
        d = *(const uint4*)(vbase + iv.z);
        a0 = __hfma2(w10, u2h(d.x), a0); a1 = __hfma2(w10, u2h(d.y), a1);
        a2 = __hfma2(w10, u2h(d.z), a2); a3 = __hfma2(w10, u2h(d.w), a3);
        d = *(const uint4*)(vbase + iv.w);
        a0 = __hfma2(w11, u2h(d.x), a0); a1 = __hfma2(w11, u2h(d.y), a1);
        a2 = __hfma2(w11, u2h(d.z), a2); a3 = __hfma2(w11, u2h(d.w), a3);
    }
    // vt-mix: rows split by p2 (16 each)
#pragma unroll
    for (int j = 0; j < 16; j++) {
        int r = p2 * 16 + j;
        int l = r >> 3, v = r & 7;
        __half2 wv = __float2half2_rn(SM[qs][h][l * 12 + 4 + v]);
        uint4 d = *(const uint4*)(vbase + (size_t)(LSP + r) * 512);
        a0 = __hfma2(wv, u2h(d.x), a0); a1 = __hfma2(wv, u2h(d.y), a1);
        a2 = __hfma2(wv, u2h(d.z), a2); a3 = __hfma2(wv, u2h(d.w), a3);
    }
    // reduce across the p2 halves (lane ^ 32)
    {
        int v0 = *(int*)&a0, v1 = *(int*)&a1, v2 = *(int*)&a2, v3 = *(int*)&a3;
        int u0 = __shfl_xor(v0, 32, 64), u1 = __shfl_xor(v1, 32, 64);
        int u2 = __shfl_xor(v2, 32, 64), u3 = __shfl_xor(v3, 32, 64);
        a0 = __hadd2(a0, u2h((unsigned)u0));
        a1 = __hadd2(a1, u2h((unsigned)u1));
        a2 = __hadd2(a2, u2h((unsigned)u2));
        a3 = __hadd2(a3, u2h((unsigned)u3));
    }
    if (p2 == 0) {
        float2 f0 = __half22float2(a0), f1 = __half22float2(a1);
        float2 f2 = __half22float2(a2), f3 = __half22float2(a3);
        short8 ob;
        ob[0] = (short)f2bf(f0.x); ob[1] = (short)f2bf(f0.y);
        ob[2] = (short)f2bf(f1.x); ob[3] = (short)f2bf(f1.y);
        ob[4] = (short)f2bf(f2.x); ob[5] = (short)f2bf(f2.y);
        ob[6] = (short)f2bf(f3.x); ob[7] = (short)f2bf(f3.y);
        *(short8*)(attn + (size_t)bq * 256 + h * 32 + c8) = ob;
    }
}

// ---------------- VT support kernels ----------------

__global__ __launch_bounds__(256) void vt_prep_k(const float* __restrict__ xtail, const float* __restrict__ seen,
                                                 float* __restrict__ vtsf, unsigned short* __restrict__ vtsb)
{
    const int row = blockIdx.x * 4 + (threadIdx.x >> 6);
    const int lane = threadIdx.x & 63;
    const int z = row / TVT, t = row - z * TVT;
    const int b = z >> 2, l = z & 3;
    const int c = lane * 4;
    f32x4 v;
    if (t < NVT) v = *(const f32x4*)(xtail + ((size_t)b * 32 + l * NVT + t) * 256 + c);
    else         v = *(const f32x4*)(seen + (((size_t)b * NLV + l) * NSEEN + (t - NVT)) * 256 + c);
    *(f32x4*)(vtsf + (size_t)row * 256 + c) = v;
    ushort4 ob;
    ob.x = f2bf(v.x); ob.y = f2bf(v.y); ob.z = f2bf(v.z); ob.w = f2bf(v.w);
    *(ushort4*)(vtsb + (size_t)row * 256 + c) = ob;
}

// batched MFMA GEMM over z=(b,l): per-level weights
template<int MODE>   // 0: Cf f32   3: Cb bf16(gelu)
__global__ __launch_bounds__(256) void mfma_bgemm_k(const unsigned short* __restrict__ A,
                                                    const unsigned short* __restrict__ B,
                                                    const float* __restrict__ bias,
                                                    float* __restrict__ Cf, unsigned short* __restrict__ Cb,
                                                    int M, int K, int N)
{
    __shared__ __align__(16) short As[2048];
    __shared__ __align__(16) short Bs[2048];
    const int tid = threadIdx.x;
    const int z = blockIdx.z, l = z & 3;
    const int row0 = blockIdx.x * 64;
    const int n0 = blockIdx.y * 64;
    const int w = tid >> 6, lane = tid & 63;
    const int r16 = lane & 15, q = lane >> 4;

    const int arow = min(row0 + w * 16 + r16, M - 1);
    const unsigned short* gap = A + (size_t)z * M * K + (size_t)arow * K + q * 8;
    const unsigned short* gbp = B + (size_t)l * N * K + (size_t)(n0 + w * 16 + r16) * K + q * 8;
    short* sa = As + ((w * 4 + q) * 16 + r16) * 8;
    short* sb = Bs + ((w * 4 + q) * 16 + r16) * 8;

    const int wr2 = (w >> 1) * 2;
    const int wc2 = (w & 1) * 2;

    f32x4 acc[2][2] = {};
    for (int k0 = 0; k0 < K; k0 += 32) {
        *(short8*)sa = *(const short8*)(gap + k0);
        *(short8*)sb = *(const short8*)(gbp + k0);
        __syncthreads();
        short8 af0 = *(const short8*)(As + (((wr2 + 0) * 4 + q) * 16 + r16) * 8);
        short8 af1 = *(const short8*)(As + (((wr2 + 1) * 4 + q) * 16 + r16) * 8);
        short8 bf0 = *(const short8*)(Bs + (((wc2 + 0) * 4 + q) * 16 + r16) * 8);
        short8 bf1 = *(const short8*)(Bs + (((wc2 + 1) * 4 + q) * 16 + r16) * 8);
        acc[0][0] = __builtin_amdgcn_mfma_f32_16x16x32_bf16(af0, bf0, acc[0][0], 0, 0, 0);
        acc[0][1] = __builtin_amdgcn_mfma_f32_16x16x32_bf16(af0, bf1, acc[0][1], 0, 0, 0);
        acc[1][0] = __builtin_amdgcn_mfma_f32_16x16x32_bf16(af1, bf0, acc[1][0], 0, 0, 0);
        acc[1][1] = __builtin_amdgcn_mfma_f32_16x16x32_bf16(af1, bf1, acc[1][1], 0, 0, 0);
        __syncthreads();
    }
#pragma unroll
    for (int fm = 0; fm < 2; fm++) {
#pragma unroll
        for (int fn = 0; fn < 2; fn++) {
            int col = n0 + (w & 1) * 32 + fn * 16 + r16;
            float bj = bias[l * N + col];
#pragma unroll
            for (int i = 0; i < 4; i++) {
                int row = row0 + (w >> 1) * 32 + fm * 16 + q * 4 + i;
                if (row >= M) continue;
                float v = acc[fm][fn][i] + bj;
                if (MODE == 0) Cf[(size_t)z * M * N + (size_t)row * N + col] = v;
                else {
                    float gl = v * 0.5f * (1.f + erff(v * 0.70710678118654752f));
                    Cb[(size_t)z * M * N + (size_t)row * N + col] = f2bf(gl);
                }
            }
        }
    }
}

__global__ __launch_bounds__(128) void vt_attn_k(const float* __restrict__ qkv, unsigned short* __restrict__ o)
{
    const int z = blockIdx.x;
    const int h = z & 7, bl = z >> 3;
    __shared__ float Qs[TVT][33];
    __shared__ float Ks[TVT][DHD];
    __shared__ float Vs[TVT][DHD];
    __shared__ float Ss[TVT][73];
    const int tid = threadIdx.x;
    for (int idx = tid; idx < TVT * DHD; idx += 128) {
        int t = idx >> 5, d = idx & 31;
        const float* base = qkv + ((size_t)bl * TVT + t) * 768 + h * DHD + d;
        Qs[t][d] = base[0];
        Ks[t][d] = base[256];
        Vs[t][d] = base[512];
    }
    __syncthreads();
    if (tid < TVT) {
        const float scale = 0.17677669529663687f;
        float qr[DHD];
#pragma unroll
        for (int d = 0; d < DHD; d++) qr[d] = Qs[tid][d];
        float m = -1e30f;
        for (int k = 0; k < TVT; k++) {
            float s = 0.f;
#pragma unroll
            for (int d = 0; d < DHD; d++) s = fmaf(qr[d], Ks[k][d], s);
            s *= scale;
            Ss[tid][k] = s;
            m = fmaxf(m, s);
        }
        float sum = 0.f;
        for (int k = 0; k < TVT; k++) {
            float e = __expf(Ss[tid][k] - m);
            Ss[tid][k] = e;
            sum += e;
        }
        float inv = 1.f / sum;
        for (int d = 0; d < DHD; d++) {
            float acc = 0.f;
            for (int k = 0; k < TVT; k++) acc = fmaf(Ss[tid][k], Vs[k][d], acc);
            o[((size_t)bl * TVT + tid) * D_ + h * DHD + d] = f2bf(acc * inv);
        }
    }
}

template<int ROUTE>
__global__ __launch_bounds__(256) void vt_ln_k(const float* __restrict__ y, const float* __restrict__ resid,
                                               const float* __restrict__ g, const float* __restrict__ be,
                                               float* __restrict__ dstf, unsigned short* __restrict__ dstb,
                                               float* __restrict__ out_sel, float* __restrict__ out_seen)
{
    const int row = blockIdx.x * 4 + (threadIdx.x >> 6);
    const int lane = threadIdx.x & 63;
    const int z = row / TVT, t = row - z * TVT;
    const int b = z >> 2, l = z & 3;
    const int c = lane * 4;
    f32x4 yv = *(const f32x4*)(y + (size_t)row * 256 + c);
    f32x4 rv = *(const f32x4*)(resid + (size_t)row * 256 + c);
    float t0 = yv.x + rv.x, t1 = yv.y + rv.y, t2 = yv.z + rv.z, t3 = yv.w + rv.w;
    float s = t0 + t1 + t2 + t3;
    float ss = t0 * t0 + t1 * t1 + t2 * t2 + t3 * t3;
#pragma unroll
    for (int off = 32; off; off >>= 1) {
        s += __shfl_xor(s, off, 64);
        ss += __shfl_xor(ss, off, 64);
    }
    float mean = s * (1.f / 256.f);
    float var = ss * (1.f / 256.f) - mean * mean;
    float rstd = rsqrtf(var + 1e-5f);
    f32x4 gv = *(const f32x4*)(g + l * 256 + c);
    f32x4 bv = *(const f32x4*)(be + l * 256 + c);
    f32x4 o;
    o.x = (t0 - mean) * rstd * gv.x + bv.x;
    o.y = (t1 - mean) * rstd * gv.y + bv.y;
    o.z = (t2 - mean) * rstd * gv.z + bv.z;
    o.w = (t3 - mean) * rstd * gv.w + bv.w;
    if (ROUTE == 0) {
        *(f32x4*)(dstf + (size_t)row * 256 + c) = o;
        ushort4 ob;
        ob.x = f2bf(o.x); ob.y = f2bf(o.y); ob.z = f2bf(o.z); ob.w = f2bf(o.w);
        *(ushort4*)(dstb + (size_t)row * 256 + c) = ob;
    } else {
        if (t < NVT) *(f32x4*)(out_sel + ((size_t)b * 32 + l * NVT + t) * 256 + c) = o;
        else         *(f32x4*)(out_seen + (((size_t)b * NLV + l) * NSEEN + (t - NVT)) * 256 + c) = o;
    }
}

// ---------------- launch ----------------

extern "C" void kernel_launch(void* const* d_in, const int* in_sizes, int n_in,
                              void* d_out, int out_size, void* d_ws, size_t ws_size,
                              hipStream_t stream)
{
    const float* src      = (const float*)d_in[0];
    const float* pos      = (const float*)d_in[1];
    const float* refp     = (const float*)d_in[2];
    const float* seen     = (const float*)d_in[5];
    const float* sel      = (const float*)d_in[6];
    const float* w_off    = (const float*)d_in[7];
    const float* b_off    = (const float*)d_in[8];
    const float* w_attn   = (const float*)d_in[9];
    const float* b_attn   = (const float*)d_in[10];
    const float* w_val    = (const float*)d_in[11];
    const float* b_val    = (const float*)d_in[12];
    const float* w_out    = (const float*)d_in[13];
    const float* b_out    = (const float*)d_in[14];
    const float* g1       = (const float*)d_in[15];
    const float* be1      = (const float*)d_in[16];
    const float* w_ff1    = (const float*)d_in[17];
    const float* b_ff1    = (const float*)d_in[18];
    const float* w_ff2    = (const float*)d_in[19];
    const float* b_ff2    = (const float*)d_in[20];
    const float* g2       = (const float*)d_in[21];
    const float* be2      = (const float*)d_in[22];
    const float* vt_wqkv  = (const float*)d_in[23];
    const float* vt_bqkv  = (const float*)d_in[24];
    const float* vt_wproj = (const float*)d_in[25];
    const float* vt_bproj = (const float*)d_in[26];
    const float* vt_g3    = (const float*)d_in[27];
    const float* vt_b3    = (const float*)d_in[28];
    const float* vt_g4    = (const float*)d_in[29];
    const float* vt_b4    = (const float*)d_in[30];
    const float* vt_wfc1  = (const float*)d_in[31];
    const float* vt_bfc1  = (const float*)d_in[32];
    const float* vt_wfc2  = (const float*)d_in[33];
    const float* vt_bfc2  = (const float*)d_in[34];

    float* ws = (float*)d_ws;
    // ---- workspace map (f32-word offsets), lifetimes audited (same as round 10) ----
    unsigned short* valueh = (unsigned short*)ws;              // fp16 value, words [0, 5578752)
    unsigned short* wqkvT  = (unsigned short*)(ws + 5578752);
    unsigned short* wprojT = (unsigned short*)(ws + 5971968);
    unsigned short* wfc1T  = (unsigned short*)(ws + 6103040);
    unsigned short* wfc2T  = (unsigned short*)(ws + 6627328);
    unsigned short* offbb  = (unsigned short*)(ws + 11157504);
    unsigned short* wallb  = (unsigned short*)(ws + 22315008);
    unsigned short* a0b  = (unsigned short*)(ws + 39051264);
    unsigned short* a1b  = (unsigned short*)(ws + 44630016);
    unsigned short* attn = (unsigned short*)(ws + 39051264);
    unsigned short* xb   = (unsigned short*)(ws + 44630016);
    float* y     = ws + 11157504;
    unsigned short* hb = (unsigned short*)(ws + 11157504);
    float* y2    = ws + 33472512;
    float* xtail = ws + 50208768;
    unsigned short* wtb = (unsigned short*)(ws + 50225152);
    unsigned short* wvalT  = wtb;
    unsigned short* wcatT  = wtb + 65536;
    unsigned short* woutT  = wtb + 229376;
    unsigned short* wff1T  = wtb + 294912;
    unsigned short* wff2T  = wtb + 557056;
    float* vtsf  = ws;
    float* vts2f = ws + 147456;
    float* yy    = ws + 294912;
    float* qkvf  = ws + 442368;
    unsigned short* vtsb   = (unsigned short*)(ws + 884736);
    unsigned short* vts2b  = (unsigned short*)(ws + 958464);
    unsigned short* obufb  = (unsigned short*)(ws + 1032192);
    unsigned short* hvtb   = (unsigned short*)(ws + 1105920);

    float* outx     = (float*)d_out;
    float* out_seen = outx + (size_t)BB * LSP * D_;
    float* out_sel  = out_seen + (size_t)BB * NLV * NSEEN * D_;

    // 1. all weight converts in one launch
    CvtTable tab;
    auto set = [&](int i, const float* W, unsigned short* Wt, int K, int N, int t0) {
        tab.W[i] = W; tab.Wt[i] = Wt; tab.K[i] = K; tab.N[i] = N; tab.t0[i] = t0;
    };
    set(0, w_val,    wvalT,          256, 256,  0);
    set(1, w_off,    wcatT,          256, 256,  64);
    set(2, w_attn,   wcatT + 65536,  256, 384,  128);
    set(3, w_out,    woutT,          256, 256,  224);
    set(4, w_ff1,    wff1T,          256, 1024, 288);
    set(5, w_ff2,    wff2T,          1024, 256, 544);
    set(6, vt_wqkv,  wqkvT,          256, 768,  800);
    set(7, vt_wproj, wprojT,         256, 256,  1568);
    set(8, vt_wfc1,  wfc1T,          256, 1024, 1824);
    set(9, vt_wfc2,  wfc2T,          1024, 256, 2848);
    cvt_all_k<<<3872, 256, 0, stream>>>(tab);
    // 2. input converts
    cvt_in_k<<<10896, 256, 0, stream>>>(src, pos, sel, a0b, a1b);
    // 3. projection GEMMs
    mfma_gemm128_k<4><<<dim3(MT128, 2), 256, 0, stream>>>(a0b, wvalT, b_val, nullptr, nullptr, valueh, nullptr, NBQ, 256, 256);
    mfma_gemm128_k<5><<<dim3(MT128, 5), 256, 0, stream>>>(a1b, wcatT, b_off, b_attn, nullptr, offbb, wallb, NBQ, 256, 640);
    // 4. sampling (softmax fused, 16B gathers)
    sample_k<<<NBQ / 4, 256, 0, stream>>>(valueh, offbb, wallb, refp, attn);
    // 5. out-proj (f32 y) + resid_ln -> outx/xtail f32 + xb bf16
    mfma_gemm128_k<0><<<dim3(MT128, 2), 256, 0, stream>>>(attn, woutT, b_out, nullptr, y, nullptr, nullptr, NBQ, 256, 256);
    resid_ln_k<<<NBQ / 4, 256, 0, stream>>>(y, src, sel, g1, be1, outx, xtail, xb);
    // 6. FFN: ff1 (relu bf16 hb) -> ff2 (f32 y2) -> resid_ln LN2
    mfma_gemm128_k<1><<<dim3(MT128, 8), 256, 0, stream>>>(xb, wff1T, b_ff1, nullptr, nullptr, hb, nullptr, NBQ, 256, 1024);
    mfma_gemm128_k<0><<<dim3(MT128, 2), 256, 0, stream>>>(hb, wff2T, b_ff2, nullptr, y2, nullptr, nullptr, NBQ, 1024, 256);
    resid_ln_k<<<NBQ / 4, 256, 0, stream>>>(y2, outx, xtail, g2, be2, outx, xtail, nullptr);
    // 7. VT chain
    vt_prep_k<<<NVROW / 4, 256, 0, stream>>>(xtail, seen, vtsf, vtsb);
    mfma_bgemm_k<0><<<dim3(2, 12, 8), 256, 0, stream>>>(vtsb, wqkvT, vt_bqkv, qkvf, nullptr, TVT, 256, 768);
    vt_attn_k<<<BB * NLV * NH, 128, 0, stream>>>(qkvf, obufb);
    mfma_bgemm_k<0><<<dim3(2, 4, 8),  256, 0, stream>>>(obufb, wprojT, vt_bproj, yy, nullptr, TVT, 256, 256);
    vt_ln_k<0><<<NVROW / 4, 256, 0, stream>>>(yy, vtsf, vt_g3, vt_b3, vts2f, vts2b, nullptr, nullptr);
    mfma_bgemm_k<3><<<dim3(2, 16, 8), 256, 0, stream>>>(vts2b, wfc1T, vt_bfc1, nullptr, hvtb, TVT, 256, 1024);
    mfma_bgemm_k<0><<<dim3(2, 4, 8),  256, 0, stream>>>(hvtb, wfc2T, vt_bfc2, yy, nullptr, TVT, 1024, 256);
    vt_ln_k<1><<<NVROW / 4, 256, 0, stream>>>(yy, vts2f, vt_g4, vt_b4, nullptr, nullptr, out_sel, out_seen);
}

// Round 12
// 453.847 us; speedup vs baseline: 1.4356x; 1.0973x over previous
//
#include <hip/hip_runtime.h>
#include <hip/hip_fp16.h>
#include <math.h>

#define D_    256
#define NH    8
#define DHD   32
#define NLV   4
#define NPT   4
#define NVT   8
#define NSEEN 64
#define TVT   72
#define FF    1024
#define BB    2
#define LSP   21760
#define LQ    21792
#define NBQ   (BB*LQ)      // 43584
#define NVROW (8*TVT)      // 576
#define MT128 341          // ceil(NBQ/128)

typedef __attribute__((ext_vector_type(8))) short short8;
typedef __attribute__((ext_vector_type(4))) float f32x4;

__device__ __forceinline__ unsigned short f2bf(float f)
{
    unsigned int u = __float_as_uint(f);
    u += 0x7fffu + ((u >> 16) & 1u);
    return (unsigned short)(u >> 16);
}
__device__ __forceinline__ float bf2f(unsigned short u) { return __uint_as_float((unsigned)u << 16); }
__device__ __forceinline__ __half2 u2h(unsigned int u) { return *(__half2*)&u; }
__device__ __forceinline__ unsigned int pack2(float a, float b)
{
    __half2 h = __halves2half2(__float2half_rn(a), __float2half_rn(b));
    return *(unsigned int*)&h;
}

__device__ __forceinline__ void gll16(const unsigned short* g, short* l)
{
    __builtin_amdgcn_global_load_lds((const __attribute__((address_space(1))) unsigned int*)g,
                                     (__attribute__((address_space(3))) unsigned int*)l,
                                     16, 0, 0);
}

// ---------------- batched weight transpose+convert: Wt[z][n][k] = bf16(W[z][k][n]) ----------------
struct CvtTable {
    const float* W[10];
    unsigned short* Wt[10];
    int K[10], N[10], t0[10];
};

__global__ __launch_bounds__(256) void cvt_all_k(CvtTable tab)
{
    __shared__ float T[32][33];
    const int tid = threadIdx.x;
    const int bt = blockIdx.x;
    int e = 0;
#pragma unroll
    for (int i = 1; i < 10; i++) if (bt >= tab.t0[i]) e = i;
    const int tl = bt - tab.t0[e];
    const int K = tab.K[e], N = tab.N[e];
    const int nt = N >> 5;
    const int tpz = (K >> 5) * nt;
    const int z = tl / tpz, rem = tl - z * tpz;
    const int n0 = (rem % nt) * 32, k0 = (rem / nt) * 32;
    const float* Wz = tab.W[e] + (size_t)z * K * N;
    unsigned short* Wtz = tab.Wt[e] + (size_t)z * N * K;
    const int tx = tid & 31, ty = tid >> 5;
#pragma unroll
    for (int s = 0; s < 4; s++)
        T[ty + 8 * s][tx] = Wz[(size_t)(k0 + ty + 8 * s) * N + n0 + tx];
    __syncthreads();
#pragma unroll
    for (int s = 0; s < 4; s++)
        Wtz[(size_t)(n0 + ty + 8 * s) * K + k0 + tx] = f2bf(T[tx][ty + 8 * s]);
}

// ---------------- input concat+convert ----------------
__global__ __launch_bounds__(256) void cvt_in_k(const float* __restrict__ src, const float* __restrict__ pos,
                                                const float* __restrict__ sel, unsigned short* __restrict__ a0,
                                                unsigned short* __restrict__ a1)
{
    size_t idx = ((size_t)blockIdx.x * 256 + threadIdx.x) * 4;
    int row = (int)(idx >> 8), c = (int)(idx & 255);
    int b = row / LQ, i = row - b * LQ;
    f32x4 v0, v1;
    if (i < LSP) {
        size_t g = ((size_t)b * LSP + i) * 256 + c;
        v0 = *(const f32x4*)(src + g);
        f32x4 p = *(const f32x4*)(pos + g);
        v1 = v0 + p;
    } else {
        size_t g = ((size_t)b * 32 + (i - LSP)) * 256 + c;
        v0 = *(const f32x4*)(sel + g);
        v1 = v0;
    }
    uint2 r0, r1;
    r0.x = (unsigned)f2bf(v0.x) | ((unsigned)f2bf(v0.y) << 16);
    r0.y = (unsigned)f2bf(v0.z) | ((unsigned)f2bf(v0.w) << 16);
    r1.x = (unsigned)f2bf(v1.x) | ((unsigned)f2bf(v1.y) << 16);
    r1.y = (unsigned)f2bf(v1.z) | ((unsigned)f2bf(v1.w) << 16);
    *(uint2*)(a0 + idx) = r0;
    *(uint2*)(a1 + idx) = r1;
}

// ---------------- 128x128-tile MFMA GEMM, global_load_lds staging, SWAPPED operands ----------------
// acc = mfma(bf, af): each lane holds C[row=...+r16][col base ...+q*4], 4 consecutive cols
// -> packed 8B (bf16/fp16) / 16B (f32) stores.
// MODE 0: Cf f32   MODE 1: Cb bf16(relu)   MODE 4: Cb fp16   MODE 5: split col<256->Cb, else Cb2, bf16
template<int MODE>
__global__ __launch_bounds__(256) void mfma_gemm128_k(const unsigned short* __restrict__ A,
                                                      const unsigned short* __restrict__ B,
                                                      const float* __restrict__ bias,
                                                      const float* __restrict__ bias2,
                                                      float* __restrict__ Cf,
                                                      unsigned short* __restrict__ Cb,
                                                      unsigned short* __restrict__ Cb2,
                                                      int M, int K, int N)
{
    __shared__ __align__(16) short As[4096];
    __shared__ __align__(16) short Bs[4096];
    const int tid = threadIdx.x;
    const int row0 = blockIdx.x * 128;
    const int n0 = blockIdx.y * 128;
    const int w = tid >> 6, lane = tid & 63;
    const int r16 = lane & 15, q = lane >> 4;
    const int wm = w >> 1, wn = w & 1;

    int ar0 = min(row0 + w * 16 + r16, M - 1);
    int ar1 = min(row0 + (w + 4) * 16 + r16, M - 1);
    const unsigned short* gA0 = A + (size_t)ar0 * K + q * 8;
    const unsigned short* gA1 = A + (size_t)ar1 * K + q * 8;
    const unsigned short* gB0 = B + (size_t)(n0 + w * 16 + r16) * K + q * 8;
    const unsigned short* gB1 = B + (size_t)(n0 + (w + 4) * 16 + r16) * K + q * 8;
    short* sA0 = As + ((w * 4 + q) * 16 + r16) * 8;
    short* sA1 = As + (((w + 4) * 4 + q) * 16 + r16) * 8;
    short* sB0 = Bs + ((w * 4 + q) * 16 + r16) * 8;
    short* sB1 = Bs + (((w + 4) * 4 + q) * 16 + r16) * 8;

    f32x4 acc[4][4] = {};
    for (int k0 = 0; k0 < K; k0 += 32) {
        gll16(gA0 + k0, sA0);
        gll16(gA1 + k0, sA1);
        gll16(gB0 + k0, sB0);
        gll16(gB1 + k0, sB1);
        __syncthreads();
        short8 af[4], bf[4];
#pragma unroll
        for (int i = 0; i < 4; i++) af[i] = *(const short8*)(As + (((wm * 4 + i) * 4 + q) * 16 + r16) * 8);
#pragma unroll
        for (int j = 0; j < 4; j++) bf[j] = *(const short8*)(Bs + (((wn * 4 + j) * 4 + q) * 16 + r16) * 8);
#pragma unroll
        for (int i = 0; i < 4; i++)
#pragma unroll
            for (int j = 0; j < 4; j++)
                acc[i][j] = __builtin_amdgcn_mfma_f32_16x16x32_bf16(bf[j], af[i], acc[i][j], 0, 0, 0);
        __syncthreads();
    }
    // epilogue: lane owns 4 consecutive cols per fragment
    f32x4 bj4[4];
#pragma unroll
    for (int j = 0; j < 4; j++) {
        int col = n0 + wn * 64 + j * 16 + q * 4;
        if (MODE == 5 && col >= 256) bj4[j] = *(const f32x4*)(bias2 + col - 256);
        else                         bj4[j] = *(const f32x4*)(bias + col);
    }
#pragma unroll
    for (int i = 0; i < 4; i++) {
        int row = row0 + wm * 64 + i * 16 + r16;
        if (row >= M) continue;
#pragma unroll
        for (int j = 0; j < 4; j++) {
            int col = n0 + wn * 64 + j * 16 + q * 4;
            f32x4 v = acc[i][j] + bj4[j];
            if (MODE == 0) {
                *(f32x4*)(Cf + (size_t)row * N + col) = v;
            } else if (MODE == 1) {
                ushort4 ob;
                ob.x = f2bf(fmaxf(v.x, 0.f)); ob.y = f2bf(fmaxf(v.y, 0.f));
                ob.z = f2bf(fmaxf(v.z, 0.f)); ob.w = f2bf(fmaxf(v.w, 0.f));
                *(ushort4*)(Cb + (size_t)row * N + col) = ob;
            } else if (MODE == 4) {
                ushort4 ob;
                __half h0 = __float2half(v.x), h1 = __float2half(v.y);
                __half h2 = __float2half(v.z), h3 = __float2half(v.w);
                ob.x = *(unsigned short*)&h0; ob.y = *(unsigned short*)&h1;
                ob.z = *(unsigned short*)&h2; ob.w = *(unsigned short*)&h3;
                *(ushort4*)(Cb + (size_t)row * N + col) = ob;
            } else {
                ushort4 ob;
                ob.x = f2bf(v.x); ob.y = f2bf(v.y); ob.z = f2bf(v.z); ob.w = f2bf(v.w);
                if (col < 256) *(ushort4*)(Cb + (size_t)row * 256 + col) = ob;
                else           *(ushort4*)(Cb2 + (size_t)row * 384 + col - 256) = ob;
            }
        }
    }
}

// ---------------- residual + LayerNorm (wave per row): dst = LN(y + resid); optional bf16 copy ----------------
__global__ __launch_bounds__(256) void resid_ln_k(const float* __restrict__ y, const float* __restrict__ rsp,
                                                  const float* __restrict__ rtail, const float* __restrict__ g,
                                                  const float* __restrict__ be, float* __restrict__ dsp,
                                                  float* __restrict__ dtail, unsigned short* __restrict__ dbf)
{
    const int row = blockIdx.x * 4 + (threadIdx.x >> 6);
    const int lane = threadIdx.x & 63;
    const int b = row / LQ, i = row - b * LQ;
    f32x4 yv = *(const f32x4*)(y + (size_t)row * 256 + lane * 4);
    f32x4 rv;
    size_t didx;
    float* dbase;
    if (i < LSP) { size_t gidx = ((size_t)b * LSP + i) * 256; rv = *(const f32x4*)(rsp + gidx + lane * 4); dbase = dsp; didx = gidx; }
    else         { size_t gidx = ((size_t)b * 32 + (i - LSP)) * 256; rv = *(const f32x4*)(rtail + gidx + lane * 4); dbase = dtail; didx = gidx; }
    float t0 = yv.x + rv.x, t1 = yv.y + rv.y, t2 = yv.z + rv.z, t3 = yv.w + rv.w;
    float s = t0 + t1 + t2 + t3;
    float ss = t0 * t0 + t1 * t1 + t2 * t2 + t3 * t3;
#pragma unroll
    for (int off = 32; off; off >>= 1) {
        s += __shfl_xor(s, off, 64);
        ss += __shfl_xor(ss, off, 64);
    }
    float mean = s * (1.f / 256.f);
    float var = ss * (1.f / 256.f) - mean * mean;
    float rstd = rsqrtf(var + 1e-5f);
    int c = lane * 4;
    f32x4 gv = *(const f32x4*)(g + c);
    f32x4 bv = *(const f32x4*)(be + c);
    f32x4 o;
    o.x = (t0 - mean) * rstd * gv.x + bv.x;
    o.y = (t1 - mean) * rstd * gv.y + bv.y;
    o.z = (t2 - mean) * rstd * gv.z + bv.z;
    o.w = (t3 - mean) * rstd * gv.w + bv.w;
    *(f32x4*)(dbase + didx + c) = o;
    if (dbf) {
        ushort4 ob;
        ob.x = f2bf(o.x); ob.y = f2bf(o.y); ob.z = f2bf(o.z); ob.w = f2bf(o.w);
        *(ushort4*)(dbf + (size_t)row * 256 + c) = ob;
    }
}

// ---------------- deformable sampling: fused softmax + phase-split + 16B fp16 pk-fma gather ----------------
__global__ __launch_bounds__(256) void sample_k(const unsigned short* __restrict__ value,  // fp16
                                                const unsigned short* __restrict__ offbb,  // bf16 [NBQ][256]
                                                const unsigned short* __restrict__ wallb,  // bf16 logits [NBQ][384]
                                                const float* __restrict__ refp,
                                                unsigned short* __restrict__ attn)
{
    __shared__ float SM[4][8][49];
    __shared__ float OFs[4][8][33];
    __shared__ float RPs[4][8];
    __shared__ uint2 Twt[4][4][4][8];
    __shared__ uint4 Tix[4][4][4][8];
    const int bq0 = blockIdx.x * 4;
    const int tid = threadIdx.x;
    for (int idx = tid; idx < 1536; idx += 256) {
        int qq = idx / 384, c = idx - qq * 384;
        SM[qq][c / 48][c % 48] = bf2f(wallb[(size_t)(bq0 + qq) * 384 + c]);
    }
    for (int idx = tid; idx < 1024; idx += 256) {
        int qq = idx >> 8, c = idx & 255;
        OFs[qq][c >> 5][c & 31] = bf2f(offbb[(size_t)(bq0 + qq) * 256 + c]);
    }
    if (tid < 32) RPs[tid >> 3][tid & 7] = refp[(size_t)bq0 * 8 + tid];
    __syncthreads();
    {
        int j = tid & 7, gidx = tid >> 3;
        int qq = gidx >> 3, h = gidx & 7;
        float* row = &SM[qq][h][0];
        float v[6];
#pragma unroll
        for (int k = 0; k < 6; k++) v[k] = row[j * 6 + k];
        float m = v[0];
#pragma unroll
        for (int k = 1; k < 6; k++) m = fmaxf(m, v[k]);
        m = fmaxf(m, __shfl_xor(m, 1, 64));
        m = fmaxf(m, __shfl_xor(m, 2, 64));
        m = fmaxf(m, __shfl_xor(m, 4, 64));
        float s = 0.f;
#pragma unroll
        for (int k = 0; k < 6; k++) { v[k] = __expf(v[k] - m); s += v[k]; }
        s += __shfl_xor(s, 1, 64);
        s += __shfl_xor(s, 2, 64);
        s += __shfl_xor(s, 4, 64);
        float inv = 1.f / s;
#pragma unroll
        for (int k = 0; k < 6; k++) row[j * 6 + k] = v[k] * inv;
    }
    __syncthreads();
    const int HLc[4] = {128, 64, 32, 16};
    const int S0c[4] = {0, 16384, 20480, 21504};
#pragma unroll
    for (int s = 0; s < 2; s++) {
        int tt = tid + 256 * s;
        int qq = tt >> 7, l = (tt >> 5) & 3, p = (tt >> 3) & 3, h = tt & 7;
        int Wl = HLc[l], s0 = S0c[l];
        float x = RPs[qq][l * 2 + 0] * (float)Wl - 0.5f + OFs[qq][h][l * 8 + p * 2 + 0];
        float y = RPs[qq][l * 2 + 1] * (float)Wl - 0.5f + OFs[qq][h][l * 8 + p * 2 + 1];
        float wgt = SM[qq][h][l * 12 + p];
        float x0f = floorf(x), y0f = floorf(y);
        int x0 = (int)x0f, y0 = (int)y0f;
        float fx = x - x0f, fy = y - y0f;
        float vx0 = (x0 >= 0 && x0 <= Wl - 1) ? 1.f : 0.f;
        float vx1 = (x0 >= -1 && x0 <= Wl - 2) ? 1.f : 0.f;
        float vy0 = (y0 >= 0 && y0 <= Wl - 1) ? 1.f : 0.f;
        float vy1 = (y0 >= -1 && y0 <= Wl - 2) ? 1.f : 0.f;
        float w00 = (1.f - fx) * (1.f - fy) * wgt * vx0 * vy0;
        float w01 = fx * (1.f - fy) * wgt * vx1 * vy0;
        float w10 = (1.f - fx) * fy * wgt * vx0 * vy1;
        float w11 = fx * fy * wgt * vx1 * vy1;
        int x0c = min(max(x0, 0), Wl - 1), x1c = min(max(x0 + 1, 0), Wl - 1);
        int y0c = min(max(y0, 0), Wl - 1), y1c = min(max(y0 + 1, 0), Wl - 1);
        int rb0 = (s0 + y0c * Wl) * 512, rb1 = (s0 + y1c * Wl) * 512;
        Twt[qq][l][p][h] = make_uint2(pack2(w00, w01), pack2(w10, w11));
        Tix[qq][l][p][h] = make_uint4(rb0 + x0c * 512, rb0 + x1c * 512, rb1 + x0c * 512, rb1 + x1c * 512);
    }
    __syncthreads();
    // phase 2: 16B gathers; p2 = point-parity half-wave
    const int qs = tid >> 6, lane = tid & 63;
    const int p2 = lane >> 5;
    const int h = (lane >> 2) & 7;
    const int c8 = (lane & 3) * 8;
    const int bq = bq0 + qs, b = bq / LQ;
    const char* vbase = (const char*)value + ((size_t)b * LQ * 256 + h * 32 + c8) * 2;
    __half2 a0 = __float2half2_rn(0.f), a1 = a0, a2 = a0, a3 = a0;
#pragma unroll
    for (int it = 0; it < 8; it++) {
        const int l = it >> 1;
        const int p = (it & 1) * 2 + p2;
        uint2 wp = *(const uint2*)&Twt[qs][l][p][h];
        uint4 iv = *(const uint4*)&Tix[qs][l][p][h];
        __half2 wx = u2h(wp.x), wy = u2h(wp.y);
        __half2 w00 = __low2half2(wx), w01 = __high2half2(wx);
        __half2 w10 = __low2half2(wy), w11 = __high2half2(wy);
        uint4 d;
        d = *(const uint4*)(vbase + iv.x);
        a0 = __hfma2(w00, u2h(d.x), a0); a1 = __hfma2(w00, u2h(d.y), a1);
        a2 = __hfma2(w00, u2h(d.z), a2); a3 = __hfma2(w00, u2h(d.w), a3);
        d = *(const uint4*)(vbase + iv.y);
        a0 = __hfma2(w01, u2h(d.x), a0); a1 = __hfma2(w01, u2h(d.y), a1);
        a2 = __hfma2(w01, u2h(d.z), a2); a3 = __hfma2(w01, u2h(d.w), a3);
        d = *(const uint4*)(vbase + iv.z);
        a0 = __hfma2(w10, u2h(d.x), a0); a1 = __hfma2(w10, u2h(d.y), a1);
        a2 = __hfma2(w10, u2h(d.z), a2); a3 = __hfma2(w10, u2h(d.w), a3);
        d = *(const uint4*)(vbase + iv.w);
        a0 = __hfma2(w11, u2h(d.x), a0); a1 = __hfma2(w11, u2h(d.y), a1);
        a2 = __hfma2(w11, u2h(d.z), a2); a3 = __hfma2(w11, u2h(d.w), a3);
    }
    // vt-mix: rows split by p2 (16 each)
#pragma unroll
    for (int j = 0; j < 16; j++) {
        int r = p2 * 16 + j;
        int l = r >> 3, v = r & 7;
        __half2 wv = __float2half2_rn(SM[qs][h][l * 12 + 4 + v]);
        uint4 d = *(const uint4*)(vbase + (size_t)(LSP + r) * 512);
        a0 = __hfma2(wv, u2h(d.x), a0); a1 = __hfma2(wv, u2h(d.y), a1);
        a2 = __hfma2(wv, u2h(d.z), a2); a3 = __hfma2(wv, u2h(d.w), a3);
    }
    // reduce across the p2 halves (lane ^ 32)
    {
        int v0 = *(int*)&a0, v1 = *(int*)&a1, v2 = *(int*)&a2, v3 = *(int*)&a3;
        int u0 = __shfl_xor(v0, 32, 64), u1 = __shfl_xor(v1, 32, 64);
        int u2 = __shfl_xor(v2, 32, 64), u3 = __shfl_xor(v3, 32, 64);
        a0 = __hadd2(a0, u2h((unsigned)u0));
        a1 = __hadd2(a1, u2h((unsigned)u1));
        a2 = __hadd2(a2, u2h((unsigned)u2));
        a3 = __hadd2(a3, u2h((unsigned)u3));
    }
    if (p2 == 0) {
        float2 f0 = __half22float2(a0), f1 = __half22float2(a1);
        float2 f2 = __half22float2(a2), f3 = __half22float2(a3);
        short8 ob;
        ob[0] = (short)f2bf(f0.x); ob[1] = (short)f2bf(f0.y);
        ob[2] = (short)f2bf(f1.x); ob[3] = (short)f2bf(f1.y);
        ob[4] = (short)f2bf(f2.x); ob[5] = (short)f2bf(f2.y);
        ob[6] = (short)f2bf(f3.x); ob[7] = (short)f2bf(f3.y);
        *(short8*)(attn + (size_t)bq * 256 + h * 32 + c8) = ob;
    }
}

// ---------------- VT support kernels ----------------

__global__ __launch_bounds__(256) void vt_prep_k(const float* __restrict__ xtail, const float* __restrict__ seen,
                                                 float* __restrict__ vtsf, unsigned short* __restrict__ vtsb)
{
    const int row = blockIdx.x * 4 + (threadIdx.x >> 6);
    const int lane = threadIdx.x & 63;
    const int z = row / TVT, t = row - z * TVT;
    const int b = z >> 2, l = z & 3;
    const int c = lane * 4;
    f32x4 v;
    if (t < NVT) v = *(const f32x4*)(xtail + ((size_t)b * 32 + l * NVT + t) * 256 + c);
    else         v = *(const f32x4*)(seen + (((size_t)b * NLV + l) * NSEEN + (t - NVT)) * 256 + c);
    *(f32x4*)(vtsf + (size_t)row * 256 + c) = v;
    ushort4 ob;
    ob.x = f2bf(v.x); ob.y = f2bf(v.y); ob.z = f2bf(v.z); ob.w = f2bf(v.w);
    *(ushort4*)(vtsb + (size_t)row * 256 + c) = ob;
}

// batched MFMA GEMM over z=(b,l): per-level weights
template<int MODE>   // 0: Cf f32   3: Cb bf16(gelu)
__global__ __launch_bounds__(256) void mfma_bgemm_k(const unsigned short* __restrict__ A,
                                                    const unsigned short* __restrict__ B,
                                                    const float* __restrict__ bias,
                                                    float* __restrict__ Cf, unsigned short* __restrict__ Cb,
                                                    int M, int K, int N)
{
    __shared__ __align__(16) short As[2048];
    __shared__ __align__(16) short Bs[2048];
    const int tid = threadIdx.x;
    const int z = blockIdx.z, l = z & 3;
    const int row0 = blockIdx.x * 64;
    const int n0 = blockIdx.y * 64;
    const int w = tid >> 6, lane = tid & 63;
    const int r16 = lane & 15, q = lane >> 4;

    const int arow = min(row0 + w * 16 + r16, M - 1);
    const unsigned short* gap = A + (size_t)z * M * K + (size_t)arow * K + q * 8;
    const unsigned short* gbp = B + (size_t)l * N * K + (size_t)(n0 + w * 16 + r16) * K + q * 8;
    short* sa = As + ((w * 4 + q) * 16 + r16) * 8;
    short* sb = Bs + ((w * 4 + q) * 16 + r16) * 8;

    const int wr2 = (w >> 1) * 2;
    const int wc2 = (w & 1) * 2;

    f32x4 acc[2][2] = {};
    for (int k0 = 0; k0 < K; k0 += 32) {
        *(short8*)sa = *(const short8*)(gap + k0);
        *(short8*)sb = *(const short8*)(gbp + k0);
        __syncthreads();
        short8 af0 = *(const short8*)(As + (((wr2 + 0) * 4 + q) * 16 + r16) * 8);
        short8 af1 = *(const short8*)(As + (((wr2 + 1) * 4 + q) * 16 + r16) * 8);
        short8 bf0 = *(const short8*)(Bs + (((wc2 + 0) * 4 + q) * 16 + r16) * 8);
        short8 bf1 = *(const short8*)(Bs + (((wc2 + 1) * 4 + q) * 16 + r16) * 8);
        acc[0][0] = __builtin_amdgcn_mfma_f32_16x16x32_bf16(af0, bf0, acc[0][0], 0, 0, 0);
        acc[0][1] = __builtin_amdgcn_mfma_f32_16x16x32_bf16(af0, bf1, acc[0][1], 0, 0, 0);
        acc[1][0] = __builtin_amdgcn_mfma_f32_16x16x32_bf16(af1, bf0, acc[1][0], 0, 0, 0);
        acc[1][1] = __builtin_amdgcn_mfma_f32_16x16x32_bf16(af1, bf1, acc[1][1], 0, 0, 0);
        __syncthreads();
    }
#pragma unroll
    for (int fm = 0; fm < 2; fm++) {
#pragma unroll
        for (int fn = 0; fn < 2; fn++) {
            int col = n0 + (w & 1) * 32 + fn * 16 + r16;
            float bj = bias[l * N + col];
#pragma unroll
            for (int i = 0; i < 4; i++) {
                int row = row0 + (w >> 1) * 32 + fm * 16 + q * 4 + i;
                if (row >= M) continue;
                float v = acc[fm][fn][i] + bj;
                if (MODE == 0) Cf[(size_t)z * M * N + (size_t)row * N + col] = v;
                else {
                    float gl = v * 0.5f * (1.f + erff(v * 0.70710678118654752f));
                    Cb[(size_t)z * M * N + (size_t)row * N + col] = f2bf(gl);
                }
            }
        }
    }
}

__global__ __launch_bounds__(128) void vt_attn_k(const float* __restrict__ qkv, unsigned short* __restrict__ o)
{
    const int z = blockIdx.x;
    const int h = z & 7, bl = z >> 3;
    __shared__ float Qs[TVT][33];
    __shared__ float Ks[TVT][DHD];
    __shared__ float Vs[TVT][DHD];
    __shared__ float Ss[TVT][73];
    const int tid = threadIdx.x;
    for (int idx = tid; idx < TVT * DHD; idx += 128) {
        int t = idx >> 5, d = idx & 31;
        const float* base = qkv + ((size_t)bl * TVT + t) * 768 + h * DHD + d;
        Qs[t][d] = base[0];
        Ks[t][d] = base[256];
        Vs[t][d] = base[512];
    }
    __syncthreads();
    if (tid < TVT) {
        const float scale = 0.17677669529663687f;
        float qr[DHD];
#pragma unroll
        for (int d = 0; d < DHD; d++) qr[d] = Qs[tid][d];
        float m = -1e30f;
        for (int k = 0; k < TVT; k++) {
            float s = 0.f;
#pragma unroll
            for (int d = 0; d < DHD; d++) s = fmaf(qr[d], Ks[k][d], s);
            s *= scale;
            Ss[tid][k] = s;
            m = fmaxf(m, s);
        }
        float sum = 0.f;
        for (int k = 0; k < TVT; k++) {
            float e = __expf(Ss[tid][k] - m);
            Ss[tid][k] = e;
            sum += e;
        }
        float inv = 1.f / sum;
        for (int d = 0; d < DHD; d++) {
            float acc = 0.f;
            for (int k = 0; k < TVT; k++) acc = fmaf(Ss[tid][k], Vs[k][d], acc);
            o[((size_t)bl * TVT + tid) * D_ + h * DHD + d] = f2bf(acc * inv);
        }
    }
}

template<int ROUTE>
__global__ __launch_bounds__(256) void vt_ln_k(const float* __restrict__ y, const float* __restrict__ resid,
                                               const float* __restrict__ g, const float* __restrict__ be,
                                               float* __restrict__ dstf, unsigned short* __restrict__ dstb,
                                               float* __restrict__ out_sel, float* __restrict__ out_seen)
{
    const int row = blockIdx.x * 4 + (threadIdx.x >> 6);
    const int lane = threadIdx.x & 63;
    const int z = row / TVT, t = row - z * TVT;
    const int b = z >> 2, l = z & 3;
    const int c = lane * 4;
    f32x4 yv = *(const f32x4*)(y + (size_t)row * 256 + c);
    f32x4 rv = *(const f32x4*)(resid + (size_t)row * 256 + c);
    float t0 = yv.x + rv.x, t1 = yv.y + rv.y, t2 = yv.z + rv.z, t3 = yv.w + rv.w;
    float s = t0 + t1 + t2 + t3;
    float ss = t0 * t0 + t1 * t1 + t2 * t2 + t3 * t3;
#pragma unroll
    for (int off = 32; off; off >>= 1) {
        s += __shfl_xor(s, off, 64);
        ss += __shfl_xor(ss, off, 64);
    }
    float mean = s * (1.f / 256.f);
    float var = ss * (1.f / 256.f) - mean * mean;
    float rstd = rsqrtf(var + 1e-5f);
    f32x4 gv = *(const f32x4*)(g + l * 256 + c);
    f32x4 bv = *(const f32x4*)(be + l * 256 + c);
    f32x4 o;
    o.x = (t0 - mean) * rstd * gv.x + bv.x;
    o.y = (t1 - mean) * rstd * gv.y + bv.y;
    o.z = (t2 - mean) * rstd * gv.z + bv.z;
    o.w = (t3 - mean) * rstd * gv.w + bv.w;
    if (ROUTE == 0) {
        *(f32x4*)(dstf + (size_t)row * 256 + c) = o;
        ushort4 ob;
        ob.x = f2bf(o.x); ob.y = f2bf(o.y); ob.z = f2bf(o.z); ob.w = f2bf(o.w);
        *(ushort4*)(dstb + (size_t)row * 256 + c) = ob;
    } else {
        if (t < NVT) *(f32x4*)(out_sel + ((size_t)b * 32 + l * NVT + t) * 256 + c) = o;
        else         *(f32x4*)(out_seen + (((size_t)b * NLV + l) * NSEEN + (t - NVT)) * 256 + c) = o;
    }
}

// ---------------- launch ----------------

extern "C" void kernel_launch(void* const* d_in, const int* in_sizes, int n_in,
                              void* d_out, int out_size, void* d_ws, size_t ws_size,
                              hipStream_t stream)
{
    const float* src      = (const float*)d_in[0];
    const float* pos      = (const float*)d_in[1];
    const float* refp     = (const float*)d_in[2];
    const float* seen     = (const float*)d_in[5];
    const float* sel      = (const float*)d_in[6];
    const float* w_off    = (const float*)d_in[7];
    const float* b_off    = (const float*)d_in[8];
    const float* w_attn   = (const float*)d_in[9];
    const float* b_attn   = (const float*)d_in[10];
    const float* w_val    = (const float*)d_in[11];
    const float* b_val    = (const float*)d_in[12];
    const float* w_out    = (const float*)d_in[13];
    const float* b_out    = (const float*)d_in[14];
    const float* g1       = (const float*)d_in[15];
    const float* be1      = (const float*)d_in[16];
    const float* w_ff1    = (const float*)d_in[17];
    const float* b_ff1    = (const float*)d_in[18];
    const float* w_ff2    = (const float*)d_in[19];
    const float* b_ff2    = (const float*)d_in[20];
    const float* g2       = (const float*)d_in[21];
    const float* be2      = (const float*)d_in[22];
    const float* vt_wqkv  = (const float*)d_in[23];
    const float* vt_bqkv  = (const float*)d_in[24];
    const float* vt_wproj = (const float*)d_in[25];
    const float* vt_bproj = (const float*)d_in[26];
    const float* vt_g3    = (const float*)d_in[27];
    const float* vt_b3    = (const float*)d_in[28];
    const float* vt_g4    = (const float*)d_in[29];
    const float* vt_b4    = (const float*)d_in[30];
    const float* vt_wfc1  = (const float*)d_in[31];
    const float* vt_bfc1  = (const float*)d_in[32];
    const float* vt_wfc2  = (const float*)d_in[33];
    const float* vt_bfc2  = (const float*)d_in[34];

    float* ws = (float*)d_ws;
    // ---- workspace map (f32-word offsets), lifetimes audited (same as round 10/11) ----
    unsigned short* valueh = (unsigned short*)ws;              // fp16 value, words [0, 5578752)
    unsigned short* wqkvT  = (unsigned short*)(ws + 5578752);
    unsigned short* wprojT = (unsigned short*)(ws + 5971968);
    unsigned short* wfc1T  = (unsigned short*)(ws + 6103040);
    unsigned short* wfc2T  = (unsigned short*)(ws + 6627328);
    unsigned short* offbb  = (unsigned short*)(ws + 11157504);
    unsigned short* wallb  = (unsigned short*)(ws + 22315008);
    unsigned short* a0b  = (unsigned short*)(ws + 39051264);
    unsigned short* a1b  = (unsigned short*)(ws + 44630016);
    unsigned short* attn = (unsigned short*)(ws + 39051264);
    unsigned short* xb   = (unsigned short*)(ws + 44630016);
    float* y     = ws + 11157504;
    unsigned short* hb = (unsigned short*)(ws + 11157504);
    float* y2    = ws + 33472512;
    float* xtail = ws + 50208768;
    unsigned short* wtb = (unsigned short*)(ws + 50225152);
    unsigned short* wvalT  = wtb;
    unsigned short* wcatT  = wtb + 65536;
    unsigned short* woutT  = wtb + 229376;
    unsigned short* wff1T  = wtb + 294912;
    unsigned short* wff2T  = wtb + 557056;
    float* vtsf  = ws;
    float* vts2f = ws + 147456;
    float* yy    = ws + 294912;
    float* qkvf  = ws + 442368;
    unsigned short* vtsb   = (unsigned short*)(ws + 884736);
    unsigned short* vts2b  = (unsigned short*)(ws + 958464);
    unsigned short* obufb  = (unsigned short*)(ws + 1032192);
    unsigned short* hvtb   = (unsigned short*)(ws + 1105920);

    float* outx     = (float*)d_out;
    float* out_seen = outx + (size_t)BB * LSP * D_;
    float* out_sel  = out_seen + (size_t)BB * NLV * NSEEN * D_;

    // 1. all weight converts in one launch
    CvtTable tab;
    auto set = [&](int i, const float* W, unsigned short* Wt, int K, int N, int t0) {
        tab.W[i] = W; tab.Wt[i] = Wt; tab.K[i] = K; tab.N[i] = N; tab.t0[i] = t0;
    };
    set(0, w_val,    wvalT,          256, 256,  0);
    set(1, w_off,    wcatT,          256, 256,  64);
    set(2, w_attn,   wcatT + 65536,  256, 384,  128);
    set(3, w_out,    woutT,          256, 256,  224);
    set(4, w_ff1,    wff1T,          256, 1024, 288);
    set(5, w_ff2,    wff2T,          1024, 256, 544);
    set(6, vt_wqkv,  wqkvT,          256, 768,  800);
    set(7, vt_wproj, wprojT,         256, 256,  1568);
    set(8, vt_wfc1,  wfc1T,          256, 1024, 1824);
    set(9, vt_wfc2,  wfc2T,          1024, 256, 2848);
    cvt_all_k<<<3872, 256, 0, stream>>>(tab);
    // 2. input converts
    cvt_in_k<<<10896, 256, 0, stream>>>(src, pos, sel, a0b, a1b);
    // 3. projection GEMMs
    mfma_gemm128_k<4><<<dim3(MT128, 2), 256, 0, stream>>>(a0b, wvalT, b_val, nullptr, nullptr, valueh, nullptr, NBQ, 256, 256);
    mfma_gemm128_k<5><<<dim3(MT128, 5), 256, 0, stream>>>(a1b, wcatT, b_off, b_attn, nullptr, offbb, wallb, NBQ, 256, 640);
    // 4. sampling (softmax fused, 16B gathers)
    sample_k<<<NBQ / 4, 256, 0, stream>>>(valueh, offbb, wallb, refp, attn);
    // 5. out-proj (f32 y) + resid_ln -> outx/xtail f32 + xb bf16
    mfma_gemm128_k<0><<<dim3(MT128, 2), 256, 0, stream>>>(attn, woutT, b_out, nullptr, y, nullptr, nullptr, NBQ, 256, 256);
    resid_ln_k<<<NBQ / 4, 256, 0, stream>>>(y, src, sel, g1, be1, outx, xtail, xb);
    // 6. FFN: ff1 (relu bf16 hb) -> ff2 (f32 y2) -> resid_ln LN2
    mfma_gemm128_k<1><<<dim3(MT128, 8), 256, 0, stream>>>(xb, wff1T, b_ff1, nullptr, nullptr, hb, nullptr, NBQ, 256, 1024);
    mfma_gemm128_k<0><<<dim3(MT128, 2), 256, 0, stream>>>(hb, wff2T, b_ff2, nullptr, y2, nullptr, nullptr, NBQ, 1024, 256);
    resid_ln_k<<<NBQ / 4, 256, 0, stream>>>(y2, outx, xtail, g2, be2, outx, xtail, nullptr);
    // 7. VT chain
    vt_prep_k<<<NVROW / 4, 256, 0, stream>>>(xtail, seen, vtsf, vtsb);
    mfma_bgemm_k<0><<<dim3(2, 12, 8), 256, 0, stream>>>(vtsb, wqkvT, vt_bqkv, qkvf, nullptr, TVT, 256, 768);
    vt_attn_k<<<BB * NLV * NH, 128, 0, stream>>>(qkvf, obufb);
    mfma_bgemm_k<0><<<dim3(2, 4, 8),  256, 0, stream>>>(obufb, wprojT, vt_bproj, yy, nullptr, TVT, 256, 256);
    vt_ln_k<0><<<NVROW / 4, 256, 0, stream>>>(yy, vtsf, vt_g3, vt_b3, vts2f, vts2b, nullptr, nullptr);
    mfma_bgemm_k<3><<<dim3(2, 16, 8), 256, 0, stream>>>(vts2b, wfc1T, vt_bfc1, nullptr, hvtb, TVT, 256, 1024);
    mfma_bgemm_k<0><<<dim3(2, 4, 8),  256, 0, stream>>>(hvtb, wfc2T, vt_bfc2, yy, nullptr, TVT, 1024, 256);
    vt_ln_k<1><<<NVROW / 4, 256, 0, stream>>>(yy, vts2f, vt_g4, vt_b4, nullptr, nullptr, out_sel, out_seen);
}

// Round 13
// 441.577 us; speedup vs baseline: 1.4755x; 1.0278x over previous
//
#include <hip/hip_runtime.h>
#include <hip/hip_fp16.h>
#include <math.h>

#define D_    256
#define NH    8
#define DHD   32
#define NLV   4
#define NPT   4
#define NVT   8
#define NSEEN 64
#define TVT   72
#define FF    1024
#define BB    2
#define LSP   21760
#define LQ    21792
#define NBQ   (BB*LQ)      // 43584
#define NVROW (8*TVT)      // 576
#define MT128 341          // ceil(NBQ/128)

typedef __attribute__((ext_vector_type(8))) short short8;
typedef __attribute__((ext_vector_type(4))) float f32x4;

__device__ __forceinline__ unsigned short f2bf(float f)
{
    unsigned int u = __float_as_uint(f);
    u += 0x7fffu + ((u >> 16) & 1u);
    return (unsigned short)(u >> 16);
}
__device__ __forceinline__ float bf2f(unsigned short u) { return __uint_as_float((unsigned)u << 16); }
__device__ __forceinline__ __half2 u2h(unsigned int u) { return *(__half2*)&u; }
__device__ __forceinline__ unsigned int pack2(float a, float b)
{
    __half2 h = __halves2half2(__float2half_rn(a), __float2half_rn(b));
    return *(unsigned int*)&h;
}

__device__ __forceinline__ void gll16(const unsigned short* g, short* l)
{
    __builtin_amdgcn_global_load_lds((const __attribute__((address_space(1))) unsigned int*)g,
                                     (__attribute__((address_space(3))) unsigned int*)l,
                                     16, 0, 0);
}

// ---------------- batched weight transpose+convert: Wt[z][n][k] = bf16(W[z][k][n]) ----------------
struct CvtTable {
    const float* W[10];
    unsigned short* Wt[10];
    int K[10], N[10], t0[10];
};

__global__ __launch_bounds__(256) void cvt_all_k(CvtTable tab)
{
    __shared__ float T[32][33];
    const int tid = threadIdx.x;
    const int bt = blockIdx.x;
    int e = 0;
#pragma unroll
    for (int i = 1; i < 10; i++) if (bt >= tab.t0[i]) e = i;
    const int tl = bt - tab.t0[e];
    const int K = tab.K[e], N = tab.N[e];
    const int nt = N >> 5;
    const int tpz = (K >> 5) * nt;
    const int z = tl / tpz, rem = tl - z * tpz;
    const int n0 = (rem % nt) * 32, k0 = (rem / nt) * 32;
    const float* Wz = tab.W[e] + (size_t)z * K * N;
    unsigned short* Wtz = tab.Wt[e] + (size_t)z * N * K;
    const int tx = tid & 31, ty = tid >> 5;
#pragma unroll
    for (int s = 0; s < 4; s++)
        T[ty + 8 * s][tx] = Wz[(size_t)(k0 + ty + 8 * s) * N + n0 + tx];
    __syncthreads();
#pragma unroll
    for (int s = 0; s < 4; s++)
        Wtz[(size_t)(n0 + ty + 8 * s) * K + k0 + tx] = f2bf(T[tx][ty + 8 * s]);
}

// ---------------- input concat+convert ----------------
__global__ __launch_bounds__(256) void cvt_in_k(const float* __restrict__ src, const float* __restrict__ pos,
                                                const float* __restrict__ sel, unsigned short* __restrict__ a0,
                                                unsigned short* __restrict__ a1)
{
    size_t idx = ((size_t)blockIdx.x * 256 + threadIdx.x) * 4;
    int row = (int)(idx >> 8), c = (int)(idx & 255);
    int b = row / LQ, i = row - b * LQ;
    f32x4 v0, v1;
    if (i < LSP) {
        size_t g = ((size_t)b * LSP + i) * 256 + c;
        v0 = *(const f32x4*)(src + g);
        f32x4 p = *(const f32x4*)(pos + g);
        v1 = v0 + p;
    } else {
        size_t g = ((size_t)b * 32 + (i - LSP)) * 256 + c;
        v0 = *(const f32x4*)(sel + g);
        v1 = v0;
    }
    uint2 r0, r1;
    r0.x = (unsigned)f2bf(v0.x) | ((unsigned)f2bf(v0.y) << 16);
    r0.y = (unsigned)f2bf(v0.z) | ((unsigned)f2bf(v0.w) << 16);
    r1.x = (unsigned)f2bf(v1.x) | ((unsigned)f2bf(v1.y) << 16);
    r1.y = (unsigned)f2bf(v1.z) | ((unsigned)f2bf(v1.w) << 16);
    *(uint2*)(a0 + idx) = r0;
    *(uint2*)(a1 + idx) = r1;
}

// ---------------- 128x128-tile MFMA GEMM, global_load_lds staging, swapped operands ----------------
// MODE 0: Cf f32   MODE 1: Cb bf16(relu)   MODE 2: Cb bf16   MODE 4: Cb fp16
// MODE 5: split col<256 -> Cb [row*256] (bias), else Cb2 [row*512, padded] (bias2), bf16
template<int MODE>
__global__ __launch_bounds__(256) void mfma_gemm128_k(const unsigned short* __restrict__ A,
                                                      const unsigned short* __restrict__ B,
                                                      const float* __restrict__ bias,
                                                      const float* __restrict__ bias2,
                                                      float* __restrict__ Cf,
                                                      unsigned short* __restrict__ Cb,
                                                      unsigned short* __restrict__ Cb2,
                                                      int M, int K, int N)
{
    __shared__ __align__(16) short As[4096];
    __shared__ __align__(16) short Bs[4096];
    const int tid = threadIdx.x;
    const int row0 = blockIdx.x * 128;
    const int n0 = blockIdx.y * 128;
    const int w = tid >> 6, lane = tid & 63;
    const int r16 = lane & 15, q = lane >> 4;
    const int wm = w >> 1, wn = w & 1;

    int ar0 = min(row0 + w * 16 + r16, M - 1);
    int ar1 = min(row0 + (w + 4) * 16 + r16, M - 1);
    const unsigned short* gA0 = A + (size_t)ar0 * K + q * 8;
    const unsigned short* gA1 = A + (size_t)ar1 * K + q * 8;
    const unsigned short* gB0 = B + (size_t)(n0 + w * 16 + r16) * K + q * 8;
    const unsigned short* gB1 = B + (size_t)(n0 + (w + 4) * 16 + r16) * K + q * 8;
    short* sA0 = As + ((w * 4 + q) * 16 + r16) * 8;
    short* sA1 = As + (((w + 4) * 4 + q) * 16 + r16) * 8;
    short* sB0 = Bs + ((w * 4 + q) * 16 + r16) * 8;
    short* sB1 = Bs + (((w + 4) * 4 + q) * 16 + r16) * 8;

    f32x4 acc[4][4] = {};
    for (int k0 = 0; k0 < K; k0 += 32) {
        gll16(gA0 + k0, sA0);
        gll16(gA1 + k0, sA1);
        gll16(gB0 + k0, sB0);
        gll16(gB1 + k0, sB1);
        __syncthreads();
        short8 af[4], bf[4];
#pragma unroll
        for (int i = 0; i < 4; i++) af[i] = *(const short8*)(As + (((wm * 4 + i) * 4 + q) * 16 + r16) * 8);
#pragma unroll
        for (int j = 0; j < 4; j++) bf[j] = *(const short8*)(Bs + (((wn * 4 + j) * 4 + q) * 16 + r16) * 8);
#pragma unroll
        for (int i = 0; i < 4; i++)
#pragma unroll
            for (int j = 0; j < 4; j++)
                acc[i][j] = __builtin_amdgcn_mfma_f32_16x16x32_bf16(bf[j], af[i], acc[i][j], 0, 0, 0);
        __syncthreads();
    }
    f32x4 bj4[4];
#pragma unroll
    for (int j = 0; j < 4; j++) {
        int col = n0 + wn * 64 + j * 16 + q * 4;
        if (MODE == 5 && col >= 256) bj4[j] = *(const f32x4*)(bias2 + col - 256);
        else                         bj4[j] = *(const f32x4*)(bias + col);
    }
#pragma unroll
    for (int i = 0; i < 4; i++) {
        int row = row0 + wm * 64 + i * 16 + r16;
        if (row >= M) continue;
#pragma unroll
        for (int j = 0; j < 4; j++) {
            int col = n0 + wn * 64 + j * 16 + q * 4;
            f32x4 v = acc[i][j] + bj4[j];
            if (MODE == 0) {
                *(f32x4*)(Cf + (size_t)row * N + col) = v;
            } else if (MODE == 1) {
                ushort4 ob;
                ob.x = f2bf(fmaxf(v.x, 0.f)); ob.y = f2bf(fmaxf(v.y, 0.f));
                ob.z = f2bf(fmaxf(v.z, 0.f)); ob.w = f2bf(fmaxf(v.w, 0.f));
                *(ushort4*)(Cb + (size_t)row * N + col) = ob;
            } else if (MODE == 2) {
                ushort4 ob;
                ob.x = f2bf(v.x); ob.y = f2bf(v.y); ob.z = f2bf(v.z); ob.w = f2bf(v.w);
                *(ushort4*)(Cb + (size_t)row * N + col) = ob;
            } else if (MODE == 4) {
                ushort4 ob;
                __half h0 = __float2half(v.x), h1 = __float2half(v.y);
                __half h2 = __float2half(v.z), h3 = __float2half(v.w);
                ob.x = *(unsigned short*)&h0; ob.y = *(unsigned short*)&h1;
                ob.z = *(unsigned short*)&h2; ob.w = *(unsigned short*)&h3;
                *(ushort4*)(Cb + (size_t)row * N + col) = ob;
            } else {
                ushort4 ob;
                ob.x = f2bf(v.x); ob.y = f2bf(v.y); ob.z = f2bf(v.z); ob.w = f2bf(v.w);
                if (col < 256) *(ushort4*)(Cb + (size_t)row * 256 + col) = ob;
                else           *(ushort4*)(Cb2 + (size_t)row * 512 + col - 256) = ob;
            }
        }
    }
}

// ---------------- residual + LayerNorm (wave per row): dst = LN(bf16 y + resid); optional bf16 copy ----------------
__global__ __launch_bounds__(256) void resid_ln_k(const unsigned short* __restrict__ yb, const float* __restrict__ rsp,
                                                  const float* __restrict__ rtail, const float* __restrict__ g,
                                                  const float* __restrict__ be, float* __restrict__ dsp,
                                                  float* __restrict__ dtail, unsigned short* __restrict__ dbf)
{
    const int row = blockIdx.x * 4 + (threadIdx.x >> 6);
    const int lane = threadIdx.x & 63;
    const int b = row / LQ, i = row - b * LQ;
    ushort4 yu = *(const ushort4*)(yb + (size_t)row * 256 + lane * 4);
    f32x4 yv;
    yv.x = bf2f(yu.x); yv.y = bf2f(yu.y); yv.z = bf2f(yu.z); yv.w = bf2f(yu.w);
    f32x4 rv;
    size_t didx;
    float* dbase;
    if (i < LSP) { size_t gidx = ((size_t)b * LSP + i) * 256; rv = *(const f32x4*)(rsp + gidx + lane * 4); dbase = dsp; didx = gidx; }
    else         { size_t gidx = ((size_t)b * 32 + (i - LSP)) * 256; rv = *(const f32x4*)(rtail + gidx + lane * 4); dbase = dtail; didx = gidx; }
    float t0 = yv.x + rv.x, t1 = yv.y + rv.y, t2 = yv.z + rv.z, t3 = yv.w + rv.w;
    float s = t0 + t1 + t2 + t3;
    float ss = t0 * t0 + t1 * t1 + t2 * t2 + t3 * t3;
#pragma unroll
    for (int off = 32; off; off >>= 1) {
        s += __shfl_xor(s, off, 64);
        ss += __shfl_xor(ss, off, 64);
    }
    float mean = s * (1.f / 256.f);
    float var = ss * (1.f / 256.f) - mean * mean;
    float rstd = rsqrtf(var + 1e-5f);
    int c = lane * 4;
    f32x4 gv = *(const f32x4*)(g + c);
    f32x4 bv = *(const f32x4*)(be + c);
    f32x4 o;
    o.x = (t0 - mean) * rstd * gv.x + bv.x;
    o.y = (t1 - mean) * rstd * gv.y + bv.y;
    o.z = (t2 - mean) * rstd * gv.z + bv.z;
    o.w = (t3 - mean) * rstd * gv.w + bv.w;
    *(f32x4*)(dbase + didx + c) = o;
    if (dbf) {
        ushort4 ob;
        ob.x = f2bf(o.x); ob.y = f2bf(o.y); ob.z = f2bf(o.z); ob.w = f2bf(o.w);
        *(ushort4*)(dbf + (size_t)row * 256 + c) = ob;
    }
}

// ---------------- deformable sampling: fused softmax (flat SM, div-free staging) + 16B fp16 gather ----------------
__global__ __launch_bounds__(256) void sample_k(const unsigned short* __restrict__ value,  // fp16
                                                const unsigned short* __restrict__ offbb,  // bf16 [NBQ][256]
                                                const unsigned short* __restrict__ wallb,  // bf16 logits [NBQ][512] padded
                                                const float* __restrict__ refp,
                                                unsigned short* __restrict__ attn)
{
    __shared__ float SM4[4 * 384 + 16];  // flat [qq*384 + h*48 + slot]
    __shared__ float OFs[4][8][33];
    __shared__ float RPs[4][8];
    __shared__ uint2 Twt[4][4][4][8];
    __shared__ uint4 Tix[4][4][4][8];
    const int bq0 = blockIdx.x * 4;
    const int tid = threadIdx.x;
    // stage logits (div-free: row stride 512, uint loads)
#pragma unroll
    for (int it = 0; it < 4; it++) {
        int idx = tid + it * 256;               // 0..1023 uints
        int qq = idx >> 8, cu = idx & 255;
        int c = cu * 2;
        if (c < 384) {
            unsigned int u = *(const unsigned int*)(wallb + (size_t)(bq0 + qq) * 512 + c);
            SM4[qq * 384 + c]     = bf2f((unsigned short)(u & 0xffffu));
            SM4[qq * 384 + c + 1] = bf2f((unsigned short)(u >> 16));
        }
    }
#pragma unroll
    for (int it = 0; it < 4; it++) {
        int idx = tid + it * 256;
        int qq = idx >> 8, c = idx & 255;
        OFs[qq][c >> 5][c & 31] = bf2f(offbb[(size_t)(bq0 + qq) * 256 + c]);
    }
    if (tid < 32) RPs[tid >> 3][tid & 7] = refp[(size_t)bq0 * 8 + tid];
    __syncthreads();
    // softmax-48 per (q,h): 8 lanes x 6 elems
    {
        int j = tid & 7, gidx = tid >> 3;
        int qq = gidx >> 3, h = gidx & 7;
        float* row = &SM4[qq * 384 + h * 48];
        float v[6];
#pragma unroll
        for (int k = 0; k < 6; k++) v[k] = row[j * 6 + k];
        float m = v[0];
#pragma unroll
        for (int k = 1; k < 6; k++) m = fmaxf(m, v[k]);
        m = fmaxf(m, __shfl_xor(m, 1, 64));
        m = fmaxf(m, __shfl_xor(m, 2, 64));
        m = fmaxf(m, __shfl_xor(m, 4, 64));
        float s = 0.f;
#pragma unroll
        for (int k = 0; k < 6; k++) { v[k] = __expf(v[k] - m); s += v[k]; }
        s += __shfl_xor(s, 1, 64);
        s += __shfl_xor(s, 2, 64);
        s += __shfl_xor(s, 4, 64);
        float inv = 1.f / s;
#pragma unroll
        for (int k = 0; k < 6; k++) row[j * 6 + k] = v[k] * inv;
    }
    __syncthreads();
    const int HLc[4] = {128, 64, 32, 16};
    const int S0c[4] = {0, 16384, 20480, 21504};
#pragma unroll
    for (int s = 0; s < 2; s++) {
        int tt = tid + 256 * s;
        int qq = tt >> 7, l = (tt >> 5) & 3, p = (tt >> 3) & 3, h = tt & 7;
        int Wl = HLc[l], s0 = S0c[l];
        float x = RPs[qq][l * 2 + 0] * (float)Wl - 0.5f + OFs[qq][h][l * 8 + p * 2 + 0];
        float y = RPs[qq][l * 2 + 1] * (float)Wl - 0.5f + OFs[qq][h][l * 8 + p * 2 + 1];
        float wgt = SM4[qq * 384 + h * 48 + l * 12 + p];
        float x0f = floorf(x), y0f = floorf(y);
        int x0 = (int)x0f, y0 = (int)y0f;
        float fx = x - x0f, fy = y - y0f;
        float vx0 = (x0 >= 0 && x0 <= Wl - 1) ? 1.f : 0.f;
        float vx1 = (x0 >= -1 && x0 <= Wl - 2) ? 1.f : 0.f;
        float vy0 = (y0 >= 0 && y0 <= Wl - 1) ? 1.f : 0.f;
        float vy1 = (y0 >= -1 && y0 <= Wl - 2) ? 1.f : 0.f;
        float w00 = (1.f - fx) * (1.f - fy) * wgt * vx0 * vy0;
        float w01 = fx * (1.f - fy) * wgt * vx1 * vy0;
        float w10 = (1.f - fx) * fy * wgt * vx0 * vy1;
        float w11 = fx * fy * wgt * vx1 * vy1;
        int x0c = min(max(x0, 0), Wl - 1), x1c = min(max(x0 + 1, 0), Wl - 1);
        int y0c = min(max(y0, 0), Wl - 1), y1c = min(max(y0 + 1, 0), Wl - 1);
        int rb0 = (s0 + y0c * Wl) * 512, rb1 = (s0 + y1c * Wl) * 512;
        Twt[qq][l][p][h] = make_uint2(pack2(w00, w01), pack2(w10, w11));
        Tix[qq][l][p][h] = make_uint4(rb0 + x0c * 512, rb0 + x1c * 512, rb1 + x0c * 512, rb1 + x1c * 512);
    }
    __syncthreads();
    // phase 2: 16B gathers; p2 = point-parity half-wave
    const int qs = tid >> 6, lane = tid & 63;
    const int p2 = lane >> 5;
    const int h = (lane >> 2) & 7;
    const int c8 = (lane & 3) * 8;
    const int bq = bq0 + qs, b = bq / LQ;
    const char* vbase = (const char*)value + ((size_t)b * LQ * 256 + h * 32 + c8) * 2;
    __half2 a0 = __float2half2_rn(0.f), a1 = a0, a2 = a0, a3 = a0;
#pragma unroll
    for (int it = 0; it < 8; it++) {
        const int l = it >> 1;
        const int p = (it & 1) * 2 + p2;
        uint2 wp = *(const uint2*)&Twt[qs][l][p][h];
        uint4 iv = *(const uint4*)&Tix[qs][l][p][h];
        __half2 wx = u2h(wp.x), wy = u2h(wp.y);
        __half2 w00 = __low2half2(wx), w01 = __high2half2(wx);
        __half2 w10 = __low2half2(wy), w11 = __high2half2(wy);
        uint4 d;
        d = *(const uint4*)(vbase + iv.x);
        a0 = __hfma2(w00, u2h(d.x), a0); a1 = __hfma2(w00, u2h(d.y), a1);
        a2 = __hfma2(w00, u2h(d.z), a2); a3 = __hfma2(w00, u2h(d.w), a3);
        d = *(const uint4*)(vbase + iv.y);
        a0 = __hfma2(w01, u2h(d.x), a0); a1 = __hfma2(w01, u2h(d.y), a1);
        a2 = __hfma2(w01, u2h(d.z), a2); a3 = __hfma2(w01, u2h(d.w), a3);
        d = *(const uint4*)(vbase + iv.z);
        a0 = __hfma2(w10, u2h(d.x), a0); a1 = __hfma2(w10, u2h(d.y), a1);
        a2 = __hfma2(w10, u2h(d.z), a2); a3 = __hfma2(w10, u2h(d.w), a3);
        d = *(const uint4*)(vbase + iv.w);
        a0 = __hfma2(w11, u2h(d.x), a0); a1 = __hfma2(w11, u2h(d.y), a1);
        a2 = __hfma2(w11, u2h(d.z), a2); a3 = __hfma2(w11, u2h(d.w), a3);
    }
#pragma unroll
    for (int j = 0; j < 16; j++) {
        int r = p2 * 16 + j;
        int l = r >> 3, v = r & 7;
        __half2 wv = __float2half2_rn(SM4[qs * 384 + h * 48 + l * 12 + 4 + v]);
        uint4 d = *(const uint4*)(vbase + (size_t)(LSP + r) * 512);
        a0 = __hfma2(wv, u2h(d.x), a0); a1 = __hfma2(wv, u2h(d.y), a1);
        a2 = __hfma2(wv, u2h(d.z), a2); a3 = __hfma2(wv, u2h(d.w), a3);
    }
    {
        int v0 = *(int*)&a0, v1 = *(int*)&a1, v2 = *(int*)&a2, v3 = *(int*)&a3;
        int u0 = __shfl_xor(v0, 32, 64), u1 = __shfl_xor(v1, 32, 64);
        int u2 = __shfl_xor(v2, 32, 64), u3 = __shfl_xor(v3, 32, 64);
        a0 = __hadd2(a0, u2h((unsigned)u0));
        a1 = __hadd2(a1, u2h((unsigned)u1));
        a2 = __hadd2(a2, u2h((unsigned)u2));
        a3 = __hadd2(a3, u2h((unsigned)u3));
    }
    if (p2 == 0) {
        float2 f0 = __half22float2(a0), f1 = __half22float2(a1);
        float2 f2 = __half22float2(a2), f3 = __half22float2(a3);
        short8 ob;
        ob[0] = (short)f2bf(f0.x); ob[1] = (short)f2bf(f0.y);
        ob[2] = (short)f2bf(f1.x); ob[3] = (short)f2bf(f1.y);
        ob[4] = (short)f2bf(f2.x); ob[5] = (short)f2bf(f2.y);
        ob[6] = (short)f2bf(f3.x); ob[7] = (short)f2bf(f3.y);
        *(short8*)(attn + (size_t)bq * 256 + h * 32 + c8) = ob;
    }
}

// ---------------- VT support kernels ----------------

__global__ __launch_bounds__(256) void vt_prep_k(const float* __restrict__ xtail, const float* __restrict__ seen,
                                                 float* __restrict__ vtsf, unsigned short* __restrict__ vtsb)
{
    const int row = blockIdx.x * 4 + (threadIdx.x >> 6);
    const int lane = threadIdx.x & 63;
    const int z = row / TVT, t = row - z * TVT;
    const int b = z >> 2, l = z & 3;
    const int c = lane * 4;
    f32x4 v;
    if (t < NVT) v = *(const f32x4*)(xtail + ((size_t)b * 32 + l * NVT + t) * 256 + c);
    else         v = *(const f32x4*)(seen + (((size_t)b * NLV + l) * NSEEN + (t - NVT)) * 256 + c);
    *(f32x4*)(vtsf + (size_t)row * 256 + c) = v;
    ushort4 ob;
    ob.x = f2bf(v.x); ob.y = f2bf(v.y); ob.z = f2bf(v.z); ob.w = f2bf(v.w);
    *(ushort4*)(vtsb + (size_t)row * 256 + c) = ob;
}

template<int MODE>   // 0: Cf f32   3: Cb bf16(gelu)
__global__ __launch_bounds__(256) void mfma_bgemm_k(const unsigned short* __restrict__ A,
                                                    const unsigned short* __restrict__ B,
                                                    const float* __restrict__ bias,
                                                    float* __restrict__ Cf, unsigned short* __restrict__ Cb,
                                                    int M, int K, int N)
{
    __shared__ __align__(16) short As[2048];
    __shared__ __align__(16) short Bs[2048];
    const int tid = threadIdx.x;
    const int z = blockIdx.z, l = z & 3;
    const int row0 = blockIdx.x * 64;
    const int n0 = blockIdx.y * 64;
    const int w = tid >> 6, lane = tid & 63;
    const int r16 = lane & 15, q = lane >> 4;

    const int arow = min(row0 + w * 16 + r16, M - 1);
    const unsigned short* gap = A + (size_t)z * M * K + (size_t)arow * K + q * 8;
    const unsigned short* gbp = B + (size_t)l * N * K + (size_t)(n0 + w * 16 + r16) * K + q * 8;
    short* sa = As + ((w * 4 + q) * 16 + r16) * 8;
    short* sb = Bs + ((w * 4 + q) * 16 + r16) * 8;

    const int wr2 = (w >> 1) * 2;
    const int wc2 = (w & 1) * 2;

    f32x4 acc[2][2] = {};
    for (int k0 = 0; k0 < K; k0 += 32) {
        *(short8*)sa = *(const short8*)(gap + k0);
        *(short8*)sb = *(const short8*)(gbp + k0);
        __syncthreads();
        short8 af0 = *(const short8*)(As + (((wr2 + 0) * 4 + q) * 16 + r16) * 8);
        short8 af1 = *(const short8*)(As + (((wr2 + 1) * 4 + q) * 16 + r16) * 8);
        short8 bf0 = *(const short8*)(Bs + (((wc2 + 0) * 4 + q) * 16 + r16) * 8);
        short8 bf1 = *(const short8*)(Bs + (((wc2 + 1) * 4 + q) * 16 + r16) * 8);
        acc[0][0] = __builtin_amdgcn_mfma_f32_16x16x32_bf16(af0, bf0, acc[0][0], 0, 0, 0);
        acc[0][1] = __builtin_amdgcn_mfma_f32_16x16x32_bf16(af0, bf1, acc[0][1], 0, 0, 0);
        acc[1][0] = __builtin_amdgcn_mfma_f32_16x16x32_bf16(af1, bf0, acc[1][0], 0, 0, 0);
        acc[1][1] = __builtin_amdgcn_mfma_f32_16x16x32_bf16(af1, bf1, acc[1][1], 0, 0, 0);
        __syncthreads();
    }
#pragma unroll
    for (int fm = 0; fm < 2; fm++) {
#pragma unroll
        for (int fn = 0; fn < 2; fn++) {
            int col = n0 + (w & 1) * 32 + fn * 16 + r16;
            float bj = bias[l * N + col];
#pragma unroll
            for (int i = 0; i < 4; i++) {
                int row = row0 + (w >> 1) * 32 + fm * 16 + q * 4 + i;
                if (row >= M) continue;
                float v = acc[fm][fn][i] + bj;
                if (MODE == 0) Cf[(size_t)z * M * N + (size_t)row * N + col] = v;
                else {
                    float gl = v * 0.5f * (1.f + erff(v * 0.70710678118654752f));
                    Cb[(size_t)z * M * N + (size_t)row * N + col] = f2bf(gl);
                }
            }
        }
    }
}

__global__ __launch_bounds__(128) void vt_attn_k(const float* __restrict__ qkv, unsigned short* __restrict__ o)
{
    const int z = blockIdx.x;
    const int h = z & 7, bl = z >> 3;
    __shared__ float Qs[TVT][33];
    __shared__ float Ks[TVT][DHD];
    __shared__ float Vs[TVT][DHD];
    __shared__ float Ss[TVT][73];
    const int tid = threadIdx.x;
    for (int idx = tid; idx < TVT * DHD; idx += 128) {
        int t = idx >> 5, d = idx & 31;
        const float* base = qkv + ((size_t)bl * TVT + t) * 768 + h * DHD + d;
        Qs[t][d] = base[0];
        Ks[t][d] = base[256];
        Vs[t][d] = base[512];
    }
    __syncthreads();
    if (tid < TVT) {
        const float scale = 0.17677669529663687f;
        float qr[DHD];
#pragma unroll
        for (int d = 0; d < DHD; d++) qr[d] = Qs[tid][d];
        float m = -1e30f;
        for (int k = 0; k < TVT; k++) {
            float s = 0.f;
#pragma unroll
            for (int d = 0; d < DHD; d++) s = fmaf(qr[d], Ks[k][d], s);
            s *= scale;
            Ss[tid][k] = s;
            m = fmaxf(m, s);
        }
        float sum = 0.f;
        for (int k = 0; k < TVT; k++) {
            float e = __expf(Ss[tid][k] - m);
            Ss[tid][k] = e;
            sum += e;
        }
        float inv = 1.f / sum;
        for (int d = 0; d < DHD; d++) {
            float acc = 0.f;
            for (int k = 0; k < TVT; k++) acc = fmaf(Ss[tid][k], Vs[k][d], acc);
            o[((size_t)bl * TVT + tid) * D_ + h * DHD + d] = f2bf(acc * inv);
        }
    }
}

template<int ROUTE>
__global__ __launch_bounds__(256) void vt_ln_k(const float* __restrict__ y, const float* __restrict__ resid,
                                               const float* __restrict__ g, const float* __restrict__ be,
                                               float* __restrict__ dstf, unsigned short* __restrict__ dstb,
                                               float* __restrict__ out_sel, float* __restrict__ out_seen)
{
    const int row = blockIdx.x * 4 + (threadIdx.x >> 6);
    const int lane = threadIdx.x & 63;
    const int z = row / TVT, t = row - z * TVT;
    const int b = z >> 2, l = z & 3;
    const int c = lane * 4;
    f32x4 yv = *(const f32x4*)(y + (size_t)row * 256 + c);
    f32x4 rv = *(const f32x4*)(resid + (size_t)row * 256 + c);
    float t0 = yv.x + rv.x, t1 = yv.y + rv.y, t2 = yv.z + rv.z, t3 = yv.w + rv.w;
    float s = t0 + t1 + t2 + t3;
    float ss = t0 * t0 + t1 * t1 + t2 * t2 + t3 * t3;
#pragma unroll
    for (int off = 32; off; off >>= 1) {
        s += __shfl_xor(s, off, 64);
        ss += __shfl_xor(ss, off, 64);
    }
    float mean = s * (1.f / 256.f);
    float var = ss * (1.f / 256.f) - mean * mean;
    float rstd = rsqrtf(var + 1e-5f);
    f32x4 gv = *(const f32x4*)(g + l * 256 + c);
    f32x4 bv = *(const f32x4*)(be + l * 256 + c);
    f32x4 o;
    o.x = (t0 - mean) * rstd * gv.x + bv.x;
    o.y = (t1 - mean) * rstd * gv.y + bv.y;
    o.z = (t2 - mean) * rstd * gv.z + bv.z;
    o.w = (t3 - mean) * rstd * gv.w + bv.w;
    if (ROUTE == 0) {
        *(f32x4*)(dstf + (size_t)row * 256 + c) = o;
        ushort4 ob;
        ob.x = f2bf(o.x); ob.y = f2bf(o.y); ob.z = f2bf(o.z); ob.w = f2bf(o.w);
        *(ushort4*)(dstb + (size_t)row * 256 + c) = ob;
    } else {
        if (t < NVT) *(f32x4*)(out_sel + ((size_t)b * 32 + l * NVT + t) * 256 + c) = o;
        else         *(f32x4*)(out_seen + (((size_t)b * NLV + l) * NSEEN + (t - NVT)) * 256 + c) = o;
    }
}

// ---------------- launch ----------------

extern "C" void kernel_launch(void* const* d_in, const int* in_sizes, int n_in,
                              void* d_out, int out_size, void* d_ws, size_t ws_size,
                              hipStream_t stream)
{
    const float* src      = (const float*)d_in[0];
    const float* pos      = (const float*)d_in[1];
    const float* refp     = (const float*)d_in[2];
    const float* seen     = (const float*)d_in[5];
    const float* sel      = (const float*)d_in[6];
    const float* w_off    = (const float*)d_in[7];
    const float* b_off    = (const float*)d_in[8];
    const float* w_attn   = (const float*)d_in[9];
    const float* b_attn   = (const float*)d_in[10];
    const float* w_val    = (const float*)d_in[11];
    const float* b_val    = (const float*)d_in[12];
    const float* w_out    = (const float*)d_in[13];
    const float* b_out    = (const float*)d_in[14];
    const float* g1       = (const float*)d_in[15];
    const float* be1      = (const float*)d_in[16];
    const float* w_ff1    = (const float*)d_in[17];
    const float* b_ff1    = (const float*)d_in[18];
    const float* w_ff2    = (const float*)d_in[19];
    const float* b_ff2    = (const float*)d_in[20];
    const float* g2       = (const float*)d_in[21];
    const float* be2      = (const float*)d_in[22];
    const float* vt_wqkv  = (const float*)d_in[23];
    const float* vt_bqkv  = (const float*)d_in[24];
    const float* vt_wproj = (const float*)d_in[25];
    const float* vt_bproj = (const float*)d_in[26];
    const float* vt_g3    = (const float*)d_in[27];
    const float* vt_b3    = (const float*)d_in[28];
    const float* vt_g4    = (const float*)d_in[29];
    const float* vt_b4    = (const float*)d_in[30];
    const float* vt_wfc1  = (const float*)d_in[31];
    const float* vt_bfc1  = (const float*)d_in[32];
    const float* vt_wfc2  = (const float*)d_in[33];
    const float* vt_bfc2  = (const float*)d_in[34];

    float* ws = (float*)d_ws;
    // ---- workspace map (f32-word offsets), lifetimes audited ----
    unsigned short* valueh = (unsigned short*)ws;              // fp16 value, words [0, 5578752)
    unsigned short* wqkvT  = (unsigned short*)(ws + 5578752);
    unsigned short* wprojT = (unsigned short*)(ws + 5971968);
    unsigned short* wfc1T  = (unsigned short*)(ws + 6103040);
    unsigned short* wfc2T  = (unsigned short*)(ws + 6627328);
    unsigned short* offbb  = (unsigned short*)(ws + 11157504); // bf16 [NBQ][256], words [11157504, 16736256)
    unsigned short* wallb  = (unsigned short*)(ws + 22315008); // bf16 [NBQ][512] PADDED, words [22315008, 33472512)
    unsigned short* a0b  = (unsigned short*)(ws + 39051264);
    unsigned short* a1b  = (unsigned short*)(ws + 44630016);
    unsigned short* attn = (unsigned short*)(ws + 39051264);   // over a0b (dead after value GEMM)
    unsigned short* xb   = (unsigned short*)(ws + 44630016);   // over a1b (dead after cat GEMM)
    unsigned short* yb   = (unsigned short*)(ws + 11157504);   // bf16 y, over dead offbb
    unsigned short* hb   = (unsigned short*)(ws + 11157504);   // bf16 [NBQ][1024], words [11157504, 33472512), after yb+wallb dead
    unsigned short* y2b  = (unsigned short*)(ws + 33472512);   // bf16 y2, words [33472512, 36261888), over dead attn-gap
    float* xtail = ws + 50208768;
    unsigned short* wtb = (unsigned short*)(ws + 50225152);
    unsigned short* wvalT  = wtb;
    unsigned short* wcatT  = wtb + 65536;
    unsigned short* woutT  = wtb + 229376;
    unsigned short* wff1T  = wtb + 294912;
    unsigned short* wff2T  = wtb + 557056;
    float* vtsf  = ws;
    float* vts2f = ws + 147456;
    float* yy    = ws + 294912;
    float* qkvf  = ws + 442368;
    unsigned short* vtsb   = (unsigned short*)(ws + 884736);
    unsigned short* vts2b  = (unsigned short*)(ws + 958464);
    unsigned short* obufb  = (unsigned short*)(ws + 1032192);
    unsigned short* hvtb   = (unsigned short*)(ws + 1105920);

    float* outx     = (float*)d_out;
    float* out_seen = outx + (size_t)BB * LSP * D_;
    float* out_sel  = out_seen + (size_t)BB * NLV * NSEEN * D_;

    // 1. all weight converts in one launch
    CvtTable tab;
    auto set = [&](int i, const float* W, unsigned short* Wt, int K, int N, int t0) {
        tab.W[i] = W; tab.Wt[i] = Wt; tab.K[i] = K; tab.N[i] = N; tab.t0[i] = t0;
    };
    set(0, w_val,    wvalT,          256, 256,  0);
    set(1, w_off,    wcatT,          256, 256,  64);
    set(2, w_attn,   wcatT + 65536,  256, 384,  128);
    set(3, w_out,    woutT,          256, 256,  224);
    set(4, w_ff1,    wff1T,          256, 1024, 288);
    set(5, w_ff2,    wff2T,          1024, 256, 544);
    set(6, vt_wqkv,  wqkvT,          256, 768,  800);
    set(7, vt_wproj, wprojT,         256, 256,  1568);
    set(8, vt_wfc1,  wfc1T,          256, 1024, 1824);
    set(9, vt_wfc2,  wfc2T,          1024, 256, 2848);
    cvt_all_k<<<3872, 256, 0, stream>>>(tab);
    // 2. input converts
    cvt_in_k<<<10896, 256, 0, stream>>>(src, pos, sel, a0b, a1b);
    // 3. projection GEMMs
    mfma_gemm128_k<4><<<dim3(MT128, 2), 256, 0, stream>>>(a0b, wvalT, b_val, nullptr, nullptr, valueh, nullptr, NBQ, 256, 256);
    mfma_gemm128_k<5><<<dim3(MT128, 5), 256, 0, stream>>>(a1b, wcatT, b_off, b_attn, nullptr, offbb, wallb, NBQ, 256, 640);
    // 4. sampling (softmax fused, 16B gathers, div-free staging)
    sample_k<<<NBQ / 4, 256, 0, stream>>>(valueh, offbb, wallb, refp, attn);
    // 5. out-proj (bf16 yb) + resid_ln -> outx/xtail f32 + xb bf16
    mfma_gemm128_k<2><<<dim3(MT128, 2), 256, 0, stream>>>(attn, woutT, b_out, nullptr, nullptr, yb, nullptr, NBQ, 256, 256);
    resid_ln_k<<<NBQ / 4, 256, 0, stream>>>(yb, src, sel, g1, be1, outx, xtail, xb);
    // 6. FFN: ff1 (relu bf16 hb) -> ff2 (bf16 y2b) -> resid_ln LN2
    mfma_gemm128_k<1><<<dim3(MT128, 8), 256, 0, stream>>>(xb, wff1T, b_ff1, nullptr, nullptr, hb, nullptr, NBQ, 256, 1024);
    mfma_gemm128_k<2><<<dim3(MT128, 2), 256, 0, stream>>>(hb, wff2T, b_ff2, nullptr, nullptr, y2b, nullptr, NBQ, 1024, 256);
    resid_ln_k<<<NBQ / 4, 256, 0, stream>>>(y2b, outx, xtail, g2, be2, outx, xtail, nullptr);
    // 7. VT chain
    vt_prep_k<<<NVROW / 4, 256, 0, stream>>>(xtail, seen, vtsf, vtsb);
    mfma_bgemm_k<0><<<dim3(2, 12, 8), 256, 0, stream>>>(vtsb, wqkvT, vt_bqkv, qkvf, nullptr, TVT, 256, 768);
    vt_attn_k<<<BB * NLV * NH, 128, 0, stream>>>(qkvf, obufb);
    mfma_bgemm_k<0><<<dim3(2, 4, 8),  256, 0, stream>>>(obufb, wprojT, vt_bproj, yy, nullptr, TVT, 256, 256);
    vt_ln_k<0><<<NVROW / 4, 256, 0, stream>>>(yy, vtsf, vt_g3, vt_b3, vts2f, vts2b, nullptr, nullptr);
    mfma_bgemm_k<3><<<dim3(2, 16, 8), 256, 0, stream>>>(vts2b, wfc1T, vt_bfc1, nullptr, hvtb, TVT, 256, 1024);
    mfma_bgemm_k<0><<<dim3(2, 4, 8),  256, 0, stream>>>(hvtb, wfc2T, vt_bfc2, yy, nullptr, TVT, 1024, 256);
    vt_ln_k<1><<<NVROW / 4, 256, 0, stream>>>(yy, vts2f, vt_g4, vt_b4, nullptr, nullptr, out_sel, out_seen);
}